// Round 9
// baseline (228.391 us; speedup 1.0000x reference)
//
#include <hip/hip_runtime.h>
#include <math.h>

typedef unsigned int uint;
typedef unsigned short ushort;
typedef __attribute__((ext_vector_type(8))) __bf16 bf16x8;
typedef __attribute__((ext_vector_type(2))) __bf16 bf16x2;
typedef __attribute__((ext_vector_type(4))) float f32x4;
typedef __attribute__((ext_vector_type(2))) float f32x2;

#define HW 16384   // 128*128

// ---------- helpers ----------
__device__ __forceinline__ ushort f2bf(float f) {          // fp32 -> bf16 RNE
    uint u = __float_as_uint(f);
    u += 0x7fffu + ((u >> 16) & 1u);
    return (ushort)(u >> 16);
}
// XCD-affinity swizzle: 512 blocks; remap so XCD k owns 64 contiguous (b,h)
// rows -> per-XCD L2 working set < 4 MB; producers/consumers share mapping.
__device__ __forceinline__ void bhmap(int& b, int& h) {
    int lin = blockIdx.y * (int)gridDim.x + blockIdx.x;
    int n = (lin & 7) * 64 + (lin >> 3);
    h = n & 127;
    b = n >> 7;
}
// swizzled element index into a [rows][128] bf16 LDS tile.
__device__ __forceinline__ int swz(int row, int chunk) {
    return row * 128 + ((chunk ^ (row & 15)) << 3);
}
// async 16B global -> LDS (linear dest: wave-uniform base + lane*16).
// Weight buffers are stored PRE-SWIZZLED in global (prep_w), so linear
// loads produce the same LDS contents the old reg-staged swizzled writes
// did -> MFMA reads (via swz) are bit-identical.
__device__ __forceinline__ void gl2lds16(const ushort* g, ushort* l) {
    __builtin_amdgcn_global_load_lds(
        (const __attribute__((address_space(1))) uint*)g,
        (__attribute__((address_space(3))) uint*)l,
        16, 0, 0);
}
// bilinear blend of 4 packed bf16 pairs -> packed bf16 pair.
// v5 body (bit-identical to manual RNE, verified R5/R6: absmax 0.03125):
// packed f32x2 arith (v_pk_mul/v_pk_fma) + compiler bf16 casts for the pack.
__device__ __forceinline__ uint blend2(uint a, uint b, uint c, uint d,
                                       float w00, float w01, float w10, float w11) {
    f32x2 va = { __uint_as_float(a << 16), __uint_as_float(a & 0xffff0000u) };
    f32x2 vb = { __uint_as_float(b << 16), __uint_as_float(b & 0xffff0000u) };
    f32x2 vc = { __uint_as_float(c << 16), __uint_as_float(c & 0xffff0000u) };
    f32x2 vd = { __uint_as_float(d << 16), __uint_as_float(d & 0xffff0000u) };
    f32x2 v = va * w00 + vb * w01 + vc * w10 + vd * w11;
    bf16x2 pk; pk[0] = (__bf16)v[0]; pk[1] = (__bf16)v[1];
    uint r; __builtin_memcpy(&r, &pk, 4);
    return r;
}

// ---------------------------------------------------------------------------
// Prep 1: weights -> bf16, PRE-SWIZZLED [tap][row][d] where element d of a
// row holds source ci = ((d>>3) ^ (row&15))*8 + (d&7). A linear global->LDS
// copy then reproduces the swizzled LDS tile the GEMM kernels read via swz().
// ---------------------------------------------------------------------------
__global__ __launch_bounds__(256) void prep_w(
    const float* __restrict__ wd, const float* __restrict__ w1,
    const float* __restrict__ w2, const float* __restrict__ wom,
    ushort* __restrict__ wdt, ushort* __restrict__ w1t,
    ushort* __restrict__ w2t, ushort* __restrict__ womt,
    float* __restrict__ womu)
{
    int i = blockIdx.x * 256 + threadIdx.x;
    if (i < 147456) {                       // [k][oc][d], 9*128*128
        int k = i >> 14, oc = (i >> 7) & 127, d = i & 127;
        int ci = (((d >> 3) ^ (oc & 15)) << 3) | (d & 7);
        int s = (oc * 128 + ci) * 9 + k;
        wdt[i] = f2bf(wd[s]);
        w1t[i] = f2bf(w1[s]);
        w2t[i] = f2bf(w2[s]);
    }
    if (i < 36864) {                        // [k][32][128]
        int k = i >> 12, oc = (i >> 7) & 31, d = i & 127;
        int ci = (((d >> 3) ^ (oc & 15)) << 3) | (d & 7);
        womt[i] = (oc < 27) ? f2bf(wom[(oc * 129 + ci) * 9 + k]) : (ushort)0;
    }
    if (i < 288) {                          // U-channel column: [k][32]
        int k = i >> 5, oc = i & 31;
        womu[i] = (oc < 27) ? wom[(oc * 129 + 128) * 9 + k] : 0.f;
    }
}

// ---------------------------------------------------------------------------
// Prep 2: x NCHW fp32 -> x_t NHWC bf16, LDS-transposed per (b,h) row.
// ---------------------------------------------------------------------------
__global__ __launch_bounds__(256) void prep_xt(
    const float* __restrict__ x, ushort* __restrict__ xt)
{
    int b, h; bhmap(b, h);
    const int tid = threadIdx.x;
    __shared__ __align__(16) ushort T[128 * 136];   // [w][c], pad 8
    const int w0 = tid & 127, cg = tid >> 7;
#pragma unroll 4
    for (int it = 0; it < 64; it++) {
        int c = it * 2 + cg;
        float f = x[((size_t)(b * 128 + c)) * HW + h * 128 + w0];
        T[w0 * 136 + c] = f2bf(f);
    }
    __syncthreads();
    const int w1 = tid >> 1, half = tid & 1;
    uint4* dst = (uint4*)(xt + (((size_t)b * HW) + h * 128 + w1) * 128 + half * 64);
    const uint4* src = (const uint4*)&T[w1 * 136 + half * 64];
#pragma unroll
    for (int c8 = 0; c8 < 8; c8++) dst[c8] = src[c8];
}

// ---------------------------------------------------------------------------
// k_om: offset/mask head. 512 thr, 8 waves, wave tile 16 pix x 32 oc.
// (unchanged from round-6)
// ---------------------------------------------------------------------------
__global__ __launch_bounds__(512, 4) void k_om(
    const ushort* __restrict__ xt, const float* __restrict__ U,
    const ushort* __restrict__ womt, const float* __restrict__ womu,
    const float* __restrict__ bom, float* __restrict__ omt)
{
    int b, h; bhmap(b, h);
    const int tid = threadIdx.x;
    const int wid = tid >> 6, lane = tid & 63, lq = lane & 15, quad = lane >> 4;
    const int pixbase = wid * 16;

    __shared__ __align__(16) ushort As[128 * 128];   // 32 KB
    __shared__ __align__(16) ushort Bs[32 * 128];    // 8 KB
    __shared__ float U3[3 * 130];
    __shared__ float wu[288];

    f32x4 acc[2];
#pragma unroll
    for (int j = 0; j < 2; j++)
#pragma unroll
        for (int r = 0; r < 4; r++) acc[j][r] = 0.f;

    for (int s = tid; s < 390; s += 512) {
        int r = s / 130, c = s % 130, gy = h - 1 + r, gx = c - 1;
        float v = 0.f;
        if ((unsigned)gy < 128u && (unsigned)gx < 128u) {
            v = U[(size_t)b * HW + gy * 128 + gx];
            v = fminf(fmaxf(v, 0.f), 1.f);
        }
        U3[s] = v;
    }
    if (tid < 288) wu[tid] = womu[tid];

    const int arow = tid >> 2, aq = tid & 3;         // As: 4 x 16B per thread
    for (int t9 = 0; t9 < 9; t9++) {
        int dy = t9 / 3 - 1, dx = t9 % 3 - 1;
        // Bs: one async 16B/lane -> 8 KB total (8 waves x 1 KB), linear dest
        gl2lds16(womt + t9 * 4096 + tid * 8, &Bs[wid * 512]);
        int gy = h + dy, gx = arow + dx;
        if ((unsigned)gy < 128u && (unsigned)gx < 128u) {
            const uint4* src = (const uint4*)(xt + (((size_t)b * HW) + gy * 128 + gx) * 128 + aq * 32);
#pragma unroll
            for (int c = 0; c < 4; c++) *(uint4*)&As[swz(arow, aq * 4 + c)] = src[c];
        } else {
            uint4 zz = {0, 0, 0, 0};
#pragma unroll
            for (int c = 0; c < 4; c++) *(uint4*)&As[swz(arow, aq * 4 + c)] = zz;
        }
        __syncthreads();
#pragma unroll
        for (int kk = 0; kk < 4; kk++) {
            int chunk = kk * 4 + quad;
            bf16x8 av = *(const bf16x8*)&As[swz(pixbase + lq, chunk)];
            bf16x8 bv[2];
#pragma unroll
            for (int j = 0; j < 2; j++) bv[j] = *(const bf16x8*)&Bs[swz(j * 16 + lq, chunk)];
#pragma unroll
            for (int j = 0; j < 2; j++)
                acc[j] = __builtin_amdgcn_mfma_f32_16x16x32_bf16(av, bv[j], acc[j], 0, 0, 0);
        }
        __syncthreads();
    }

    // epilogue: + bias + U-channel conv term; sigmoid for mask channels
#pragma unroll
    for (int j = 0; j < 2; j++) {
        int oc = j * 16 + lq;
        if (oc < 27) {
            float bias = bom[oc];
#pragma unroll
            for (int r = 0; r < 4; r++) {
                int pix = pixbase + quad * 4 + r;
                float v = acc[j][r] + bias;
#pragma unroll
                for (int t = 0; t < 9; t++)
                    v += U3[(t / 3) * 130 + pix + (t % 3)] * wu[t * 32 + oc];
                if (oc >= 18) v = 2.f / (1.f + __expf(-v));
                omt[((size_t)b * HW + h * 128 + pix) * 32 + oc] = v;
            }
        }
    }
}

// ---------------------------------------------------------------------------
// k_dcn: round-6 verified version (51.2 us). 128-pixel blocks (grid 512),
// 8 waves, wave tile 64 pix x 32 oc, two barriers/tap, dbuf corner table
// built during MFMA, Bs via async global_load_lds (pre-swizzled wdt),
// blend2 v5. (unchanged)
// ---------------------------------------------------------------------------
__global__ __launch_bounds__(512, 4) void k_dcn(
    const ushort* __restrict__ xt, const float* __restrict__ omt,
    const ushort* __restrict__ wdt, const float* __restrict__ bdcn,
    ushort* __restrict__ zt)
{
    int b, h; bhmap(b, h);
    const int tid = threadIdx.x;
    const int wid = tid >> 6, lane = tid & 63, lq = lane & 15, quad = lane >> 4;
    const int pixbase = (wid & 1) * 64, ocbase = (wid >> 1) * 32;

    __shared__ __align__(16) ushort As[128 * 128];   // 32 KB
    __shared__ __align__(16) ushort Bs[128 * 128];   // 32 KB
    __shared__ __align__(16) int tbl[2][128][8];     // 8 KB

    const int sc = lane & 15;        // channel chunk
    const int sp = lane >> 4;        // pixel slot

    f32x4 acc[4][2];
#pragma unroll
    for (int i = 0; i < 4; i++)
#pragma unroll
        for (int j = 0; j < 2; j++)
#pragma unroll
            for (int r = 0; r < 4; r++) acc[i][j][r] = 0.f;

    const float* omrow = omt + ((size_t)b * HW + h * 128) * 32;
    const ushort* xtb = xt + (size_t)b * HW * 128;

    auto build = [&](int k, int buf) {
        if (tid < 128) {
            int p = tid;
            float dyv = omrow[p * 32 + 2 * k];
            float dxv = omrow[p * 32 + 2 * k + 1];
            float m   = omrow[p * 32 + 18 + k];
            float fy = (float)(h + k / 3 - 1) + dyv;
            float fx = (float)(p + k % 3 - 1) + dxv;
            float y0f = floorf(fy), x0f = floorf(fx);
            float ly = fy - y0f, lx = fx - x0f;
            float hy = 1.f - ly, hx = 1.f - lx;
            bool vy0 = (y0f >= 0.f) && (y0f <= 127.f);
            bool vy1 = (y0f >= -1.f) && (y0f <= 126.f);
            bool vx0 = (x0f >= 0.f) && (x0f <= 127.f);
            bool vx1 = (x0f >= -1.f) && (x0f <= 126.f);
            float w00 = (vy0 && vx0) ? hy * hx * m : 0.f;
            float w01 = (vy0 && vx1) ? hy * lx * m : 0.f;
            float w10 = (vy1 && vx0) ? ly * hx * m : 0.f;
            float w11 = (vy1 && vx1) ? ly * lx * m : 0.f;
            int iy0 = min(max((int)y0f, 0), 127);
            int iy1 = min(max((int)y0f + 1, 0), 127);
            int ix0 = min(max((int)x0f, 0), 127);
            int ix1 = min(max((int)x0f + 1, 0), 127);
            int* tp = &tbl[buf][p][0];
            tp[0] = (iy0 * 128 + ix0) * 128;
            tp[1] = (iy0 * 128 + ix1) * 128;
            tp[2] = (iy1 * 128 + ix0) * 128;
            tp[3] = (iy1 * 128 + ix1) * 128;
            ((float*)tp)[4] = w00; ((float*)tp)[5] = w01;
            ((float*)tp)[6] = w10; ((float*)tp)[7] = w11;
        }
    };

    build(0, 0);
    __syncthreads();

    for (int k = 0; k < 9; k++) {
        const int buf = k & 1;
        // Bs: 4 async 16B/lane from pre-swizzled wdt (issued first; overlap
        // with the gather phase below; drained by the barrier)
        {
            const ushort* wsrc = wdt + (size_t)k * 16384;
#pragma unroll
            for (int c = 0; c < 4; c++)
                gl2lds16(wsrc + c * 4096 + tid * 8, &Bs[c * 4096 + wid * 512]);
        }
        // A: 4 rounds, 4 pixels per wave per round, 16 lanes span one corner row
        const ushort* basep = xtb + sc * 8;
#pragma unroll 2
        for (int r = 0; r < 4; r++) {
            int p = r * 32 + wid * 4 + sp;
            int4 off = *(const int4*)&tbl[buf][p][0];
            f32x4 wv = *(const f32x4*)((const float*)&tbl[buf][p][0] + 4);
            uint4 q00 = *(const uint4*)(basep + off.x);
            uint4 q01 = *(const uint4*)(basep + off.y);
            uint4 q10 = *(const uint4*)(basep + off.z);
            uint4 q11 = *(const uint4*)(basep + off.w);
            uint4 st;
            st.x = blend2(q00.x, q01.x, q10.x, q11.x, wv[0], wv[1], wv[2], wv[3]);
            st.y = blend2(q00.y, q01.y, q10.y, q11.y, wv[0], wv[1], wv[2], wv[3]);
            st.z = blend2(q00.z, q01.z, q10.z, q11.z, wv[0], wv[1], wv[2], wv[3]);
            st.w = blend2(q00.w, q01.w, q10.w, q11.w, wv[0], wv[1], wv[2], wv[3]);
            *(uint4*)&As[swz(p, sc)] = st;
        }
        __syncthreads();
        if (k < 8) build(k + 1, buf ^ 1);      // hides behind MFMA
#pragma unroll
        for (int kk = 0; kk < 4; kk++) {
            int chunk = kk * 4 + quad;
            bf16x8 av[4], bv[2];
#pragma unroll
            for (int i = 0; i < 4; i++) av[i] = *(const bf16x8*)&As[swz(pixbase + i * 16 + lq, chunk)];
#pragma unroll
            for (int j = 0; j < 2; j++) bv[j] = *(const bf16x8*)&Bs[swz(ocbase + j * 16 + lq, chunk)];
#pragma unroll
            for (int i = 0; i < 4; i++)
#pragma unroll
                for (int j = 0; j < 2; j++)
                    acc[i][j] = __builtin_amdgcn_mfma_f32_16x16x32_bf16(av[i], bv[j], acc[i][j], 0, 0, 0);
        }
        __syncthreads();
    }

    size_t prow = ((size_t)b * HW + h * 128) * 128;
#pragma unroll
    for (int j = 0; j < 2; j++) {
        int oc = ocbase + j * 16 + lq;
        float bias = bdcn[oc];
#pragma unroll
        for (int i = 0; i < 4; i++)
#pragma unroll
            for (int r = 0; r < 4; r++) {
                int pix = pixbase + i * 16 + quad * 4 + r;
                zt[prow + (size_t)pix * 128 + oc] = f2bf(acc[i][j][r] + bias);
            }
    }
}

// ---------------------------------------------------------------------------
// k_conv1 v8.1: r1 = relu(conv3x3(z) + b1), NHWC bf16. 512 thr, wave tile
// 64 pix x 32 oc. Structure as v8 with the two staging bugs FIXED:
//  - As[130][128] staged ONCE per dy. FIX 1: full coverage = 130 rows x 16
//    chunks = 2080 16B-chunks (v8 wrote 1040 with ch&7 -> half of every row
//    uninitialized).
//  - Placement invariant: As[r] holds z[gy][r-1]. Want z[gy][pix+dx_real],
//    dx_real = dx-1 -> row = pix + dx. FIX 2: read swz(pix + dx, chunk)
//    (v8's +1 also read row 130 OOB at pix=127,dx=2).
//  - Weights in REGISTERS, prefetched one tap ahead from pre-swizzled w1t:
//    frag(t9,j,kk) = w1t[t9*16384 + (ocbase+j*16+lq)*128 + ((kk*4+quad)^lq)*8]
//    ((ocbase+j*16+lq)&15 == lq makes this the exact old swz read).
//  - Barriers 18 -> 6. dy/dx fully unrolled; bvA/bvB statically indexed.
// VGPR budget: acc 32 + bv 64 + av 16 + addr ~12 ~= 124 < 128 cap @ (512,4).
// ---------------------------------------------------------------------------
__global__ __launch_bounds__(512, 4) void k_conv1(
    const ushort* __restrict__ zt, const ushort* __restrict__ w1t,
    const float* __restrict__ b1, ushort* __restrict__ r1t)
{
    int b, h; bhmap(b, h);
    const int tid = threadIdx.x;
    const int wid = tid >> 6, lane = tid & 63, lq = lane & 15, quad = lane >> 4;
    const int pixbase = (wid & 1) * 64, ocbase = (wid >> 1) * 32;

    __shared__ __align__(16) ushort As[130 * 128];   // 33.3 KB

    f32x4 acc[4][2];
#pragma unroll
    for (int i = 0; i < 4; i++)
#pragma unroll
        for (int j = 0; j < 2; j++)
#pragma unroll
            for (int r = 0; r < 4; r++) acc[i][j][r] = 0.f;

    // B-fragment base: + t9*16384 + j*2048 + ((kk*4+quad)^lq)*8
    const ushort* wbase = w1t + (ocbase + lq) * 128;
    auto ldbv = [&](bf16x8 (&dst)[2][4], int t9) {
#pragma unroll
        for (int j = 0; j < 2; j++)
#pragma unroll
            for (int kk = 0; kk < 4; kk++)
                dst[j][kk] = *(const bf16x8*)(wbase + t9 * 16384 + j * 2048
                                              + (((kk * 4 + quad) ^ lq) << 3));
    };

    bf16x8 bvA[2][4], bvB[2][4];
    ldbv(bvA, 0);                    // prologue: tap 0 weights

    const size_t zb = (size_t)b * HW * 128;
#pragma unroll
    for (int dyi = 0; dyi < 3; dyi++) {
        int gy = h + dyi - 1;
        // stage As rows r in [0,130): gx = r-1; 130*16 = 2080 16B-chunks
        for (int c = tid; c < 2080; c += 512) {
            int r = c >> 4, ch = c & 15, gx = r - 1;
            uint4 v = {0, 0, 0, 0};
            if ((unsigned)gy < 128u && (unsigned)gx < 128u)
                v = *(const uint4*)(zt + zb + ((size_t)gy * 128 + gx) * 128 + ch * 8);
            *(uint4*)&As[swz(r, ch)] = v;
        }
        __syncthreads();
#pragma unroll
        for (int dx = 0; dx < 3; dx++) {
            const int t9 = dyi * 3 + dx;
            bf16x8 (&cur)[2][4] = (t9 & 1) ? bvB : bvA;
            bf16x8 (&nxt)[2][4] = (t9 & 1) ? bvA : bvB;
            if (t9 < 8) ldbv(nxt, t9 + 1);   // prefetch under the MFMA burst
#pragma unroll
            for (int kk = 0; kk < 4; kk++) {
                int chunk = kk * 4 + quad;
                bf16x8 av[4];
#pragma unroll
                for (int i = 0; i < 4; i++)
                    av[i] = *(const bf16x8*)&As[swz(pixbase + i * 16 + lq + dx, chunk)];
#pragma unroll
                for (int i = 0; i < 4; i++)
#pragma unroll
                    for (int j = 0; j < 2; j++)
                        acc[i][j] = __builtin_amdgcn_mfma_f32_16x16x32_bf16(av[i], cur[j][kk], acc[i][j], 0, 0, 0);
            }
        }
        __syncthreads();
    }

    size_t prow = ((size_t)b * HW + h * 128) * 128;
#pragma unroll
    for (int j = 0; j < 2; j++) {
        int oc = ocbase + j * 16 + lq;
        float bias = b1[oc];
#pragma unroll
        for (int i = 0; i < 4; i++)
#pragma unroll
            for (int r = 0; r < 4; r++) {
                int pix = pixbase + i * 16 + quad * 4 + r;
                r1t[prow + (size_t)pix * 128 + oc] = f2bf(fmaxf(acc[i][j][r] + bias, 0.f));
            }
    }
}

// ---------------------------------------------------------------------------
// k_conv2: out = relu(x + (conv3x3(r1)+b2) * sigmoid(10*(clipU-0.5))).
// (unchanged from round-6)
// ---------------------------------------------------------------------------
__global__ __launch_bounds__(512, 4) void k_conv2(
    const ushort* __restrict__ r1t, const ushort* __restrict__ w2t,
    const float* __restrict__ b2, const float* __restrict__ x,
    const float* __restrict__ U, float* __restrict__ out)
{
    int b, h; bhmap(b, h);
    const int tid = threadIdx.x;
    const int wid = tid >> 6, lane = tid & 63, lq = lane & 15, quad = lane >> 4;
    const int mbase = (wid & 1) * 64;   // oc
    const int nbase = (wid >> 1) * 32;  // pix

    __shared__ __align__(16) ushort As[128 * 128];  // weights  [oc][ci]
    __shared__ __align__(16) ushort Bs[128 * 128];  // activ.   [pix][ci]

    f32x4 acc[4][2];
#pragma unroll
    for (int i = 0; i < 4; i++)
#pragma unroll
        for (int j = 0; j < 2; j++)
#pragma unroll
            for (int r = 0; r < 4; r++) acc[i][j][r] = 0.f;

    const int row = tid >> 2, q = tid & 3;
    for (int t9 = 0; t9 < 9; t9++) {
        int dy = t9 / 3 - 1, dx = t9 % 3 - 1;
        // As (weights): async 16B/lane x4 from pre-swizzled w2t
        {
            const ushort* wsrc = w2t + (size_t)t9 * 16384;
#pragma unroll
            for (int c = 0; c < 4; c++)
                gl2lds16(wsrc + c * 4096 + tid * 8, &As[c * 4096 + wid * 512]);
        }
        int gy = h + dy, gx = row + dx;
        if ((unsigned)gy < 128u && (unsigned)gx < 128u) {
            const uint4* src = (const uint4*)(r1t + (((size_t)b * HW) + gy * 128 + gx) * 128 + q * 32);
#pragma unroll
            for (int c = 0; c < 4; c++) *(uint4*)&Bs[swz(row, q * 4 + c)] = src[c];
        } else {
            uint4 zz = {0, 0, 0, 0};
#pragma unroll
            for (int c = 0; c < 4; c++) *(uint4*)&Bs[swz(row, q * 4 + c)] = zz;
        }
        __syncthreads();
#pragma unroll
        for (int kk = 0; kk < 4; kk++) {
            int chunk = kk * 4 + quad;
            bf16x8 av[4], bv[2];
#pragma unroll
            for (int i = 0; i < 4; i++) av[i] = *(const bf16x8*)&As[swz(mbase + i * 16 + lq, chunk)];
#pragma unroll
            for (int j = 0; j < 2; j++) bv[j] = *(const bf16x8*)&Bs[swz(nbase + j * 16 + lq, chunk)];
#pragma unroll
            for (int i = 0; i < 4; i++)
#pragma unroll
                for (int j = 0; j < 2; j++)
                    acc[i][j] = __builtin_amdgcn_mfma_f32_16x16x32_bf16(av[i], bv[j], acc[i][j], 0, 0, 0);
        }
        __syncthreads();
    }

#pragma unroll
    for (int j = 0; j < 2; j++) {
        int pix = nbase + j * 16 + lq;
        float u = U[(size_t)b * HW + h * 128 + pix];
        u = fminf(fmaxf(u, 0.f), 1.f);
        float g = 1.f / (1.f + __expf(-10.f * (u - 0.5f)));
#pragma unroll
        for (int i = 0; i < 4; i++) {
            f32x4 b4 = *(const f32x4*)&b2[mbase + i * 16 + quad * 4];
#pragma unroll
            for (int r = 0; r < 4; r++) {
                int oc = mbase + i * 16 + quad * 4 + r;
                size_t idx = ((size_t)(b * 128 + oc)) * HW + h * 128 + pix;
                float v = acc[i][j][r] + b4[r];
                out[idx] = fmaxf(x[idx] + v * g, 0.f);
            }
        }
    }
}

// ---------------------------------------------------------------------------
extern "C" void kernel_launch(void* const* d_in, const int* in_sizes, int n_in,
                              void* d_out, int out_size, void* d_ws, size_t ws_size,
                              hipStream_t stream)
{
    const float* x     = (const float*)d_in[0];
    const float* U     = (const float*)d_in[1];
    const float* w_om  = (const float*)d_in[2];
    const float* b_om  = (const float*)d_in[3];
    const float* w_dcn = (const float*)d_in[4];
    const float* b_dcn = (const float*)d_in[5];
    const float* w1    = (const float*)d_in[6];
    const float* b1    = (const float*)d_in[7];
    const float* w2    = (const float*)d_in[8];
    const float* b2    = (const float*)d_in[9];
    float* out = (float*)d_out;

    char* p = (char*)d_ws;
    ushort* xt   = (ushort*)p; p += (size_t)4 * HW * 128 * 2;   // 16.78 MB
    ushort* zt   = (ushort*)p; p += (size_t)4 * HW * 128 * 2;
    ushort* r1t  = (ushort*)p; p += (size_t)4 * HW * 128 * 2;
    float*  omt  = (float*)p;  p += (size_t)4 * HW * 32 * 4;    // 8.39 MB
    ushort* wdt  = (ushort*)p; p += 147456 * 2;
    ushort* w1t  = (ushort*)p; p += 147456 * 2;
    ushort* w2t  = (ushort*)p; p += 147456 * 2;
    ushort* womt = (ushort*)p; p += 36864 * 2;
    float*  womu = (float*)p;  p += 288 * 4;

    prep_w<<<576, 256, 0, stream>>>(w_dcn, w1, w2, w_om, wdt, w1t, w2t, womt, womu);
    prep_xt<<<dim3(128, 4), 256, 0, stream>>>(x, xt);
    k_om<<<dim3(128, 4), 512, 0, stream>>>(xt, U, womt, womu, b_om, omt);
    k_dcn<<<dim3(128, 4), 512, 0, stream>>>(xt, omt, wdt, b_dcn, zt);
    k_conv1<<<dim3(128, 4), 512, 0, stream>>>(zt, w1t, b1, r1t);
    k_conv2<<<dim3(128, 4), 512, 0, stream>>>(r1t, w2t, b2, x, U, out);
}

// Round 10
// 216.023 us; speedup vs baseline: 1.0572x; 1.0572x over previous
//
#include <hip/hip_runtime.h>
#include <math.h>

typedef unsigned int uint;
typedef unsigned short ushort;
typedef __attribute__((ext_vector_type(8))) __bf16 bf16x8;
typedef __attribute__((ext_vector_type(2))) __bf16 bf16x2;
typedef __attribute__((ext_vector_type(4))) float f32x4;
typedef __attribute__((ext_vector_type(2))) float f32x2;

#define HW 16384   // 128*128

// ---------- helpers ----------
__device__ __forceinline__ ushort f2bf(float f) {          // fp32 -> bf16 RNE
    uint u = __float_as_uint(f);
    u += 0x7fffu + ((u >> 16) & 1u);
    return (ushort)(u >> 16);
}
// XCD-affinity swizzle: 512 blocks; remap so XCD k owns 64 contiguous (b,h)
// rows -> per-XCD L2 working set < 4 MB; producers/consumers share mapping.
__device__ __forceinline__ void bhmap(int& b, int& h) {
    int lin = blockIdx.y * (int)gridDim.x + blockIdx.x;
    int n = (lin & 7) * 64 + (lin >> 3);
    h = n & 127;
    b = n >> 7;
}
// swizzled element index into a [rows][128] bf16 LDS tile.
__device__ __forceinline__ int swz(int row, int chunk) {
    return row * 128 + ((chunk ^ (row & 15)) << 3);
}
// async 16B global -> LDS (linear dest: wave-uniform base + lane*16).
// Weight buffers are stored PRE-SWIZZLED in global (prep_w), so linear
// loads produce the same LDS contents the old reg-staged swizzled writes
// did -> MFMA reads (via swz) are bit-identical.
__device__ __forceinline__ void gl2lds16(const ushort* g, ushort* l) {
    __builtin_amdgcn_global_load_lds(
        (const __attribute__((address_space(1))) uint*)g,
        (__attribute__((address_space(3))) uint*)l,
        16, 0, 0);
}
// bilinear blend of 4 packed bf16 pairs -> packed bf16 pair.
// v5 body (bit-identical to manual RNE, verified R5/R6: absmax 0.03125):
// packed f32x2 arith (v_pk_mul/v_pk_fma) + compiler bf16 casts for the pack.
__device__ __forceinline__ uint blend2(uint a, uint b, uint c, uint d,
                                       float w00, float w01, float w10, float w11) {
    f32x2 va = { __uint_as_float(a << 16), __uint_as_float(a & 0xffff0000u) };
    f32x2 vb = { __uint_as_float(b << 16), __uint_as_float(b & 0xffff0000u) };
    f32x2 vc = { __uint_as_float(c << 16), __uint_as_float(c & 0xffff0000u) };
    f32x2 vd = { __uint_as_float(d << 16), __uint_as_float(d & 0xffff0000u) };
    f32x2 v = va * w00 + vb * w01 + vc * w10 + vd * w11;
    bf16x2 pk; pk[0] = (__bf16)v[0]; pk[1] = (__bf16)v[1];
    uint r; __builtin_memcpy(&r, &pk, 4);
    return r;
}

// ---------------------------------------------------------------------------
// Prep 1: weights -> bf16, PRE-SWIZZLED [tap][row][d] where element d of a
// row holds source ci = ((d>>3) ^ (row&15))*8 + (d&7). A linear global->LDS
// copy then reproduces the swizzled LDS tile the GEMM kernels read via swz().
// ---------------------------------------------------------------------------
__global__ __launch_bounds__(256) void prep_w(
    const float* __restrict__ wd, const float* __restrict__ w1,
    const float* __restrict__ w2, const float* __restrict__ wom,
    ushort* __restrict__ wdt, ushort* __restrict__ w1t,
    ushort* __restrict__ w2t, ushort* __restrict__ womt,
    float* __restrict__ womu)
{
    int i = blockIdx.x * 256 + threadIdx.x;
    if (i < 147456) {                       // [k][oc][d], 9*128*128
        int k = i >> 14, oc = (i >> 7) & 127, d = i & 127;
        int ci = (((d >> 3) ^ (oc & 15)) << 3) | (d & 7);
        int s = (oc * 128 + ci) * 9 + k;
        wdt[i] = f2bf(wd[s]);
        w1t[i] = f2bf(w1[s]);
        w2t[i] = f2bf(w2[s]);
    }
    if (i < 36864) {                        // [k][32][128]
        int k = i >> 12, oc = (i >> 7) & 31, d = i & 127;
        int ci = (((d >> 3) ^ (oc & 15)) << 3) | (d & 7);
        womt[i] = (oc < 27) ? f2bf(wom[(oc * 129 + ci) * 9 + k]) : (ushort)0;
    }
    if (i < 288) {                          // U-channel column: [k][32]
        int k = i >> 5, oc = i & 31;
        womu[i] = (oc < 27) ? wom[(oc * 129 + 128) * 9 + k] : 0.f;
    }
}

// ---------------------------------------------------------------------------
// Prep 2: x NCHW fp32 -> x_t NHWC bf16, LDS-transposed per (b,h) row.
// ---------------------------------------------------------------------------
__global__ __launch_bounds__(256) void prep_xt(
    const float* __restrict__ x, ushort* __restrict__ xt)
{
    int b, h; bhmap(b, h);
    const int tid = threadIdx.x;
    __shared__ __align__(16) ushort T[128 * 136];   // [w][c], pad 8
    const int w0 = tid & 127, cg = tid >> 7;
#pragma unroll 4
    for (int it = 0; it < 64; it++) {
        int c = it * 2 + cg;
        float f = x[((size_t)(b * 128 + c)) * HW + h * 128 + w0];
        T[w0 * 136 + c] = f2bf(f);
    }
    __syncthreads();
    const int w1 = tid >> 1, half = tid & 1;
    uint4* dst = (uint4*)(xt + (((size_t)b * HW) + h * 128 + w1) * 128 + half * 64);
    const uint4* src = (const uint4*)&T[w1 * 136 + half * 64];
#pragma unroll
    for (int c8 = 0; c8 < 8; c8++) dst[c8] = src[c8];
}

// ---------------------------------------------------------------------------
// k_om v10: offset/mask head. 512 thr, 8 waves, wave tile 16 pix x 32 oc.
// Per-dy restructure (only proven mechanisms; weights stay in LDS):
//  - As[130][128] xt tile staged ONCE per dy (3 stagings, not 9).
//    Coverage: 130 rows x 16 chunks = 2080. Invariant: As[r] <- xt[gx=r-1];
//    want gx = pix+dx-1 -> read row pix+dx (max 129 < 130).
//  - Bs[3][32*128]: all 3 taps of the dy staged async via gl2lds per phase.
//  - Barriers 18 -> 6. Accumulation order & operand values bit-identical.
// LDS: 33.3 + 24 + ~2.7 KB ~= 60 KB -> 2 blocks/CU.
// ---------------------------------------------------------------------------
__global__ __launch_bounds__(512, 4) void k_om(
    const ushort* __restrict__ xt, const float* __restrict__ U,
    const ushort* __restrict__ womt, const float* __restrict__ womu,
    const float* __restrict__ bom, float* __restrict__ omt)
{
    int b, h; bhmap(b, h);
    const int tid = threadIdx.x;
    const int wid = tid >> 6, lane = tid & 63, lq = lane & 15, quad = lane >> 4;
    const int pixbase = wid * 16;

    __shared__ __align__(16) ushort As[130 * 128];   // 33.3 KB
    __shared__ __align__(16) ushort Bs[3][32 * 128]; // 24 KB
    __shared__ float U3[3 * 130];
    __shared__ float wu[288];

    f32x4 acc[2];
#pragma unroll
    for (int j = 0; j < 2; j++)
#pragma unroll
        for (int r = 0; r < 4; r++) acc[j][r] = 0.f;

    for (int s = tid; s < 390; s += 512) {
        int r = s / 130, c = s % 130, gy = h - 1 + r, gx = c - 1;
        float v = 0.f;
        if ((unsigned)gy < 128u && (unsigned)gx < 128u) {
            v = U[(size_t)b * HW + gy * 128 + gx];
            v = fminf(fmaxf(v, 0.f), 1.f);
        }
        U3[s] = v;
    }
    if (tid < 288) wu[tid] = womu[tid];

    const size_t xb = (size_t)b * HW * 128;
#pragma unroll
    for (int dyi = 0; dyi < 3; dyi++) {
        int gy = h + dyi - 1;
        // As: 130 rows x 16 chunks = 2080 16B-chunks over 512 threads
        for (int c = tid; c < 2080; c += 512) {
            int r = c >> 4, ch = c & 15, gx = r - 1;
            uint4 v = {0, 0, 0, 0};
            if ((unsigned)gy < 128u && (unsigned)gx < 128u)
                v = *(const uint4*)(xt + xb + ((size_t)gy * 128 + gx) * 128 + ch * 8);
            *(uint4*)&As[swz(r, ch)] = v;
        }
        // Bs: 3 taps of this dy, async 16B/lane each (pre-swizzled womt)
#pragma unroll
        for (int t = 0; t < 3; t++)
            gl2lds16(womt + (dyi * 3 + t) * 4096 + tid * 8, &Bs[t][wid * 512]);
        __syncthreads();
#pragma unroll
        for (int dx = 0; dx < 3; dx++) {
#pragma unroll
            for (int kk = 0; kk < 4; kk++) {
                int chunk = kk * 4 + quad;
                bf16x8 av = *(const bf16x8*)&As[swz(pixbase + lq + dx, chunk)];
                bf16x8 bv[2];
#pragma unroll
                for (int j = 0; j < 2; j++) bv[j] = *(const bf16x8*)&Bs[dx][swz(j * 16 + lq, chunk)];
#pragma unroll
                for (int j = 0; j < 2; j++)
                    acc[j] = __builtin_amdgcn_mfma_f32_16x16x32_bf16(av, bv[j], acc[j], 0, 0, 0);
            }
        }
        __syncthreads();
    }

    // epilogue: + bias + U-channel conv term; sigmoid for mask channels
#pragma unroll
    for (int j = 0; j < 2; j++) {
        int oc = j * 16 + lq;
        if (oc < 27) {
            float bias = bom[oc];
#pragma unroll
            for (int r = 0; r < 4; r++) {
                int pix = pixbase + quad * 4 + r;
                float v = acc[j][r] + bias;
#pragma unroll
                for (int t = 0; t < 9; t++)
                    v += U3[(t / 3) * 130 + pix + (t % 3)] * wu[t * 32 + oc];
                if (oc >= 18) v = 2.f / (1.f + __expf(-v));
                omt[((size_t)b * HW + h * 128 + pix) * 32 + oc] = v;
            }
        }
    }
}

// ---------------------------------------------------------------------------
// k_dcn: round-6 verified version (51.2 us). 128-pixel blocks (grid 512),
// 8 waves, wave tile 64 pix x 32 oc, two barriers/tap, dbuf corner table
// built during MFMA, Bs via async global_load_lds (pre-swizzled wdt),
// blend2 v5. (unchanged)
// ---------------------------------------------------------------------------
__global__ __launch_bounds__(512, 4) void k_dcn(
    const ushort* __restrict__ xt, const float* __restrict__ omt,
    const ushort* __restrict__ wdt, const float* __restrict__ bdcn,
    ushort* __restrict__ zt)
{
    int b, h; bhmap(b, h);
    const int tid = threadIdx.x;
    const int wid = tid >> 6, lane = tid & 63, lq = lane & 15, quad = lane >> 4;
    const int pixbase = (wid & 1) * 64, ocbase = (wid >> 1) * 32;

    __shared__ __align__(16) ushort As[128 * 128];   // 32 KB
    __shared__ __align__(16) ushort Bs[128 * 128];   // 32 KB
    __shared__ __align__(16) int tbl[2][128][8];     // 8 KB

    const int sc = lane & 15;        // channel chunk
    const int sp = lane >> 4;        // pixel slot

    f32x4 acc[4][2];
#pragma unroll
    for (int i = 0; i < 4; i++)
#pragma unroll
        for (int j = 0; j < 2; j++)
#pragma unroll
            for (int r = 0; r < 4; r++) acc[i][j][r] = 0.f;

    const float* omrow = omt + ((size_t)b * HW + h * 128) * 32;
    const ushort* xtb = xt + (size_t)b * HW * 128;

    auto build = [&](int k, int buf) {
        if (tid < 128) {
            int p = tid;
            float dyv = omrow[p * 32 + 2 * k];
            float dxv = omrow[p * 32 + 2 * k + 1];
            float m   = omrow[p * 32 + 18 + k];
            float fy = (float)(h + k / 3 - 1) + dyv;
            float fx = (float)(p + k % 3 - 1) + dxv;
            float y0f = floorf(fy), x0f = floorf(fx);
            float ly = fy - y0f, lx = fx - x0f;
            float hy = 1.f - ly, hx = 1.f - lx;
            bool vy0 = (y0f >= 0.f) && (y0f <= 127.f);
            bool vy1 = (y0f >= -1.f) && (y0f <= 126.f);
            bool vx0 = (x0f >= 0.f) && (x0f <= 127.f);
            bool vx1 = (x0f >= -1.f) && (x0f <= 126.f);
            float w00 = (vy0 && vx0) ? hy * hx * m : 0.f;
            float w01 = (vy0 && vx1) ? hy * lx * m : 0.f;
            float w10 = (vy1 && vx0) ? ly * hx * m : 0.f;
            float w11 = (vy1 && vx1) ? ly * lx * m : 0.f;
            int iy0 = min(max((int)y0f, 0), 127);
            int iy1 = min(max((int)y0f + 1, 0), 127);
            int ix0 = min(max((int)x0f, 0), 127);
            int ix1 = min(max((int)x0f + 1, 0), 127);
            int* tp = &tbl[buf][p][0];
            tp[0] = (iy0 * 128 + ix0) * 128;
            tp[1] = (iy0 * 128 + ix1) * 128;
            tp[2] = (iy1 * 128 + ix0) * 128;
            tp[3] = (iy1 * 128 + ix1) * 128;
            ((float*)tp)[4] = w00; ((float*)tp)[5] = w01;
            ((float*)tp)[6] = w10; ((float*)tp)[7] = w11;
        }
    };

    build(0, 0);
    __syncthreads();

    for (int k = 0; k < 9; k++) {
        const int buf = k & 1;
        // Bs: 4 async 16B/lane from pre-swizzled wdt (issued first; overlap
        // with the gather phase below; drained by the barrier)
        {
            const ushort* wsrc = wdt + (size_t)k * 16384;
#pragma unroll
            for (int c = 0; c < 4; c++)
                gl2lds16(wsrc + c * 4096 + tid * 8, &Bs[c * 4096 + wid * 512]);
        }
        // A: 4 rounds, 4 pixels per wave per round, 16 lanes span one corner row
        const ushort* basep = xtb + sc * 8;
#pragma unroll 2
        for (int r = 0; r < 4; r++) {
            int p = r * 32 + wid * 4 + sp;
            int4 off = *(const int4*)&tbl[buf][p][0];
            f32x4 wv = *(const f32x4*)((const float*)&tbl[buf][p][0] + 4);
            uint4 q00 = *(const uint4*)(basep + off.x);
            uint4 q01 = *(const uint4*)(basep + off.y);
            uint4 q10 = *(const uint4*)(basep + off.z);
            uint4 q11 = *(const uint4*)(basep + off.w);
            uint4 st;
            st.x = blend2(q00.x, q01.x, q10.x, q11.x, wv[0], wv[1], wv[2], wv[3]);
            st.y = blend2(q00.y, q01.y, q10.y, q11.y, wv[0], wv[1], wv[2], wv[3]);
            st.z = blend2(q00.z, q01.z, q10.z, q11.z, wv[0], wv[1], wv[2], wv[3]);
            st.w = blend2(q00.w, q01.w, q10.w, q11.w, wv[0], wv[1], wv[2], wv[3]);
            *(uint4*)&As[swz(p, sc)] = st;
        }
        __syncthreads();
        if (k < 8) build(k + 1, buf ^ 1);      // hides behind MFMA
#pragma unroll
        for (int kk = 0; kk < 4; kk++) {
            int chunk = kk * 4 + quad;
            bf16x8 av[4], bv[2];
#pragma unroll
            for (int i = 0; i < 4; i++) av[i] = *(const bf16x8*)&As[swz(pixbase + i * 16 + lq, chunk)];
#pragma unroll
            for (int j = 0; j < 2; j++) bv[j] = *(const bf16x8*)&Bs[swz(ocbase + j * 16 + lq, chunk)];
#pragma unroll
            for (int i = 0; i < 4; i++)
#pragma unroll
                for (int j = 0; j < 2; j++)
                    acc[i][j] = __builtin_amdgcn_mfma_f32_16x16x32_bf16(av[i], bv[j], acc[i][j], 0, 0, 0);
        }
        __syncthreads();
    }

    size_t prow = ((size_t)b * HW + h * 128) * 128;
#pragma unroll
    for (int j = 0; j < 2; j++) {
        int oc = ocbase + j * 16 + lq;
        float bias = bdcn[oc];
#pragma unroll
        for (int i = 0; i < 4; i++)
#pragma unroll
            for (int r = 0; r < 4; r++) {
                int pix = pixbase + i * 16 + quad * 4 + r;
                zt[prow + (size_t)pix * 128 + oc] = f2bf(acc[i][j][r] + bias);
            }
    }
}

// ---------------------------------------------------------------------------
// k_conv1: r1 = relu(conv3x3(z) + b1), NHWC bf16. REVERTED to round-6
// verified version (As+Bs staged per tap, Bs via gl2lds). R9 lesson:
// weights-to-registers (even one-tap-prefetched) loses to LDS fan-out —
// twice-refuted (R2, R9); do not retry.
// ---------------------------------------------------------------------------
__global__ __launch_bounds__(512, 4) void k_conv1(
    const ushort* __restrict__ zt, const ushort* __restrict__ w1t,
    const float* __restrict__ b1, ushort* __restrict__ r1t)
{
    int b, h; bhmap(b, h);
    const int tid = threadIdx.x;
    const int wid = tid >> 6, lane = tid & 63, lq = lane & 15, quad = lane >> 4;
    const int pixbase = (wid & 1) * 64, ocbase = (wid >> 1) * 32;

    __shared__ __align__(16) ushort As[128 * 128];
    __shared__ __align__(16) ushort Bs[128 * 128];

    f32x4 acc[4][2];
#pragma unroll
    for (int i = 0; i < 4; i++)
#pragma unroll
        for (int j = 0; j < 2; j++)
#pragma unroll
            for (int r = 0; r < 4; r++) acc[i][j][r] = 0.f;

    const int row = tid >> 2, q = tid & 3;
    for (int t9 = 0; t9 < 9; t9++) {
        int dy = t9 / 3 - 1, dx = t9 % 3 - 1;
        // Bs: async 16B/lane x4 from pre-swizzled w1t
        {
            const ushort* wsrc = w1t + (size_t)t9 * 16384;
#pragma unroll
            for (int c = 0; c < 4; c++)
                gl2lds16(wsrc + c * 4096 + tid * 8, &Bs[c * 4096 + wid * 512]);
        }
        int gy = h + dy, gx = row + dx;
        if ((unsigned)gy < 128u && (unsigned)gx < 128u) {
            const uint4* src = (const uint4*)(zt + (((size_t)b * HW) + gy * 128 + gx) * 128 + q * 32);
#pragma unroll
            for (int c = 0; c < 4; c++) *(uint4*)&As[swz(row, q * 4 + c)] = src[c];
        } else {
            uint4 zz = {0, 0, 0, 0};
#pragma unroll
            for (int c = 0; c < 4; c++) *(uint4*)&As[swz(row, q * 4 + c)] = zz;
        }
        __syncthreads();
#pragma unroll
        for (int kk = 0; kk < 4; kk++) {
            int chunk = kk * 4 + quad;
            bf16x8 av[4], bv[2];
#pragma unroll
            for (int i = 0; i < 4; i++) av[i] = *(const bf16x8*)&As[swz(pixbase + i * 16 + lq, chunk)];
#pragma unroll
            for (int j = 0; j < 2; j++) bv[j] = *(const bf16x8*)&Bs[swz(ocbase + j * 16 + lq, chunk)];
#pragma unroll
            for (int i = 0; i < 4; i++)
#pragma unroll
                for (int j = 0; j < 2; j++)
                    acc[i][j] = __builtin_amdgcn_mfma_f32_16x16x32_bf16(av[i], bv[j], acc[i][j], 0, 0, 0);
        }
        __syncthreads();
    }

    size_t prow = ((size_t)b * HW + h * 128) * 128;
#pragma unroll
    for (int j = 0; j < 2; j++) {
        int oc = ocbase + j * 16 + lq;
        float bias = b1[oc];
#pragma unroll
        for (int i = 0; i < 4; i++)
#pragma unroll
            for (int r = 0; r < 4; r++) {
                int pix = pixbase + i * 16 + quad * 4 + r;
                r1t[prow + (size_t)pix * 128 + oc] = f2bf(fmaxf(acc[i][j][r] + bias, 0.f));
            }
    }
}

// ---------------------------------------------------------------------------
// k_conv2: out = relu(x + (conv3x3(r1)+b2) * sigmoid(10*(clipU-0.5))).
// (unchanged from round-6)
// ---------------------------------------------------------------------------
__global__ __launch_bounds__(512, 4) void k_conv2(
    const ushort* __restrict__ r1t, const ushort* __restrict__ w2t,
    const float* __restrict__ b2, const float* __restrict__ x,
    const float* __restrict__ U, float* __restrict__ out)
{
    int b, h; bhmap(b, h);
    const int tid = threadIdx.x;
    const int wid = tid >> 6, lane = tid & 63, lq = lane & 15, quad = lane >> 4;
    const int mbase = (wid & 1) * 64;   // oc
    const int nbase = (wid >> 1) * 32;  // pix

    __shared__ __align__(16) ushort As[128 * 128];  // weights  [oc][ci]
    __shared__ __align__(16) ushort Bs[128 * 128];  // activ.   [pix][ci]

    f32x4 acc[4][2];
#pragma unroll
    for (int i = 0; i < 4; i++)
#pragma unroll
        for (int j = 0; j < 2; j++)
#pragma unroll
            for (int r = 0; r < 4; r++) acc[i][j][r] = 0.f;

    const int row = tid >> 2, q = tid & 3;
    for (int t9 = 0; t9 < 9; t9++) {
        int dy = t9 / 3 - 1, dx = t9 % 3 - 1;
        // As (weights): async 16B/lane x4 from pre-swizzled w2t
        {
            const ushort* wsrc = w2t + (size_t)t9 * 16384;
#pragma unroll
            for (int c = 0; c < 4; c++)
                gl2lds16(wsrc + c * 4096 + tid * 8, &As[c * 4096 + wid * 512]);
        }
        int gy = h + dy, gx = row + dx;
        if ((unsigned)gy < 128u && (unsigned)gx < 128u) {
            const uint4* src = (const uint4*)(r1t + (((size_t)b * HW) + gy * 128 + gx) * 128 + q * 32);
#pragma unroll
            for (int c = 0; c < 4; c++) *(uint4*)&Bs[swz(row, q * 4 + c)] = src[c];
        } else {
            uint4 zz = {0, 0, 0, 0};
#pragma unroll
            for (int c = 0; c < 4; c++) *(uint4*)&Bs[swz(row, q * 4 + c)] = zz;
        }
        __syncthreads();
#pragma unroll
        for (int kk = 0; kk < 4; kk++) {
            int chunk = kk * 4 + quad;
            bf16x8 av[4], bv[2];
#pragma unroll
            for (int i = 0; i < 4; i++) av[i] = *(const bf16x8*)&As[swz(mbase + i * 16 + lq, chunk)];
#pragma unroll
            for (int j = 0; j < 2; j++) bv[j] = *(const bf16x8*)&Bs[swz(nbase + j * 16 + lq, chunk)];
#pragma unroll
            for (int i = 0; i < 4; i++)
#pragma unroll
                for (int j = 0; j < 2; j++)
                    acc[i][j] = __builtin_amdgcn_mfma_f32_16x16x32_bf16(av[i], bv[j], acc[i][j], 0, 0, 0);
        }
        __syncthreads();
    }

#pragma unroll
    for (int j = 0; j < 2; j++) {
        int pix = nbase + j * 16 + lq;
        float u = U[(size_t)b * HW + h * 128 + pix];
        u = fminf(fmaxf(u, 0.f), 1.f);
        float g = 1.f / (1.f + __expf(-10.f * (u - 0.5f)));
#pragma unroll
        for (int i = 0; i < 4; i++) {
            f32x4 b4 = *(const f32x4*)&b2[mbase + i * 16 + quad * 4];
#pragma unroll
            for (int r = 0; r < 4; r++) {
                int oc = mbase + i * 16 + quad * 4 + r;
                size_t idx = ((size_t)(b * 128 + oc)) * HW + h * 128 + pix;
                float v = acc[i][j][r] + b4[r];
                out[idx] = fmaxf(x[idx] + v * g, 0.f);
            }
        }
    }
}

// ---------------------------------------------------------------------------
extern "C" void kernel_launch(void* const* d_in, const int* in_sizes, int n_in,
                              void* d_out, int out_size, void* d_ws, size_t ws_size,
                              hipStream_t stream)
{
    const float* x     = (const float*)d_in[0];
    const float* U     = (const float*)d_in[1];
    const float* w_om  = (const float*)d_in[2];
    const float* b_om  = (const float*)d_in[3];
    const float* w_dcn = (const float*)d_in[4];
    const float* b_dcn = (const float*)d_in[5];
    const float* w1    = (const float*)d_in[6];
    const float* b1    = (const float*)d_in[7];
    const float* w2    = (const float*)d_in[8];
    const float* b2    = (const float*)d_in[9];
    float* out = (float*)d_out;

    char* p = (char*)d_ws;
    ushort* xt   = (ushort*)p; p += (size_t)4 * HW * 128 * 2;   // 16.78 MB
    ushort* zt   = (ushort*)p; p += (size_t)4 * HW * 128 * 2;
    ushort* r1t  = (ushort*)p; p += (size_t)4 * HW * 128 * 2;
    float*  omt  = (float*)p;  p += (size_t)4 * HW * 32 * 4;    // 8.39 MB
    ushort* wdt  = (ushort*)p; p += 147456 * 2;
    ushort* w1t  = (ushort*)p; p += 147456 * 2;
    ushort* w2t  = (ushort*)p; p += 147456 * 2;
    ushort* womt = (ushort*)p; p += 36864 * 2;
    float*  womu = (float*)p;  p += 288 * 4;

    prep_w<<<576, 256, 0, stream>>>(w_dcn, w1, w2, w_om, wdt, w1t, w2t, womt, womu);
    prep_xt<<<dim3(128, 4), 256, 0, stream>>>(x, xt);
    k_om<<<dim3(128, 4), 512, 0, stream>>>(xt, U, womt, womu, b_om, omt);
    k_dcn<<<dim3(128, 4), 512, 0, stream>>>(xt, omt, wdt, b_dcn, zt);
    k_conv1<<<dim3(128, 4), 512, 0, stream>>>(zt, w1t, b1, r1t);
    k_conv2<<<dim3(128, 4), 512, 0, stream>>>(r1t, w2t, b2, x, U, out);
}

// Round 11
// 215.979 us; speedup vs baseline: 1.0575x; 1.0002x over previous
//
#include <hip/hip_runtime.h>
#include <math.h>

typedef unsigned int uint;
typedef unsigned short ushort;
typedef __attribute__((ext_vector_type(8))) __bf16 bf16x8;
typedef __attribute__((ext_vector_type(2))) __bf16 bf16x2;
typedef __attribute__((ext_vector_type(4))) float f32x4;
typedef __attribute__((ext_vector_type(2))) float f32x2;

#define HW 16384   // 128*128

// ---------- helpers ----------
__device__ __forceinline__ ushort f2bf(float f) {          // fp32 -> bf16 RNE
    uint u = __float_as_uint(f);
    u += 0x7fffu + ((u >> 16) & 1u);
    return (ushort)(u >> 16);
}
// XCD-affinity swizzle: 512 blocks; remap so XCD k owns 64 contiguous (b,h)
// rows -> per-XCD L2 working set < 4 MB; producers/consumers share mapping.
__device__ __forceinline__ void bhmap(int& b, int& h) {
    int lin = blockIdx.y * (int)gridDim.x + blockIdx.x;
    int n = (lin & 7) * 64 + (lin >> 3);
    h = n & 127;
    b = n >> 7;
}
// swizzled element index into a [rows][128] bf16 LDS tile.
__device__ __forceinline__ int swz(int row, int chunk) {
    return row * 128 + ((chunk ^ (row & 15)) << 3);
}
// async 16B global -> LDS (linear dest: wave-uniform base + lane*16).
// Weight buffers are stored PRE-SWIZZLED in global (prep_w), so linear
// loads produce the same LDS contents the old reg-staged swizzled writes
// did -> MFMA reads (via swz) are bit-identical.
__device__ __forceinline__ void gl2lds16(const ushort* g, ushort* l) {
    __builtin_amdgcn_global_load_lds(
        (const __attribute__((address_space(1))) uint*)g,
        (__attribute__((address_space(3))) uint*)l,
        16, 0, 0);
}
// bilinear blend of 4 packed bf16 pairs -> packed bf16 pair.
// v5 body (bit-identical to manual RNE, verified R5/R6: absmax 0.03125):
// packed f32x2 arith (v_pk_mul/v_pk_fma) + compiler bf16 casts for the pack.
__device__ __forceinline__ uint blend2(uint a, uint b, uint c, uint d,
                                       float w00, float w01, float w10, float w11) {
    f32x2 va = { __uint_as_float(a << 16), __uint_as_float(a & 0xffff0000u) };
    f32x2 vb = { __uint_as_float(b << 16), __uint_as_float(b & 0xffff0000u) };
    f32x2 vc = { __uint_as_float(c << 16), __uint_as_float(c & 0xffff0000u) };
    f32x2 vd = { __uint_as_float(d << 16), __uint_as_float(d & 0xffff0000u) };
    f32x2 v = va * w00 + vb * w01 + vc * w10 + vd * w11;
    bf16x2 pk; pk[0] = (__bf16)v[0]; pk[1] = (__bf16)v[1];
    uint r; __builtin_memcpy(&r, &pk, 4);
    return r;
}

// ---------------------------------------------------------------------------
// Prep 1: weights -> bf16, PRE-SWIZZLED [tap][row][d] where element d of a
// row holds source ci = ((d>>3) ^ (row&15))*8 + (d&7). A linear global->LDS
// copy then reproduces the swizzled LDS tile the GEMM kernels read via swz().
// ---------------------------------------------------------------------------
__global__ __launch_bounds__(256) void prep_w(
    const float* __restrict__ wd, const float* __restrict__ w1,
    const float* __restrict__ w2, const float* __restrict__ wom,
    ushort* __restrict__ wdt, ushort* __restrict__ w1t,
    ushort* __restrict__ w2t, ushort* __restrict__ womt,
    float* __restrict__ womu)
{
    int i = blockIdx.x * 256 + threadIdx.x;
    if (i < 147456) {                       // [k][oc][d], 9*128*128
        int k = i >> 14, oc = (i >> 7) & 127, d = i & 127;
        int ci = (((d >> 3) ^ (oc & 15)) << 3) | (d & 7);
        int s = (oc * 128 + ci) * 9 + k;
        wdt[i] = f2bf(wd[s]);
        w1t[i] = f2bf(w1[s]);
        w2t[i] = f2bf(w2[s]);
    }
    if (i < 36864) {                        // [k][32][128]
        int k = i >> 12, oc = (i >> 7) & 31, d = i & 127;
        int ci = (((d >> 3) ^ (oc & 15)) << 3) | (d & 7);
        womt[i] = (oc < 27) ? f2bf(wom[(oc * 129 + ci) * 9 + k]) : (ushort)0;
    }
    if (i < 288) {                          // U-channel column: [k][32]
        int k = i >> 5, oc = i & 31;
        womu[i] = (oc < 27) ? wom[(oc * 129 + 128) * 9 + k] : 0.f;
    }
}

// ---------------------------------------------------------------------------
// Prep 2: x NCHW fp32 -> x_t NHWC bf16, LDS-transposed per (b,h) row.
// ---------------------------------------------------------------------------
__global__ __launch_bounds__(256) void prep_xt(
    const float* __restrict__ x, ushort* __restrict__ xt)
{
    int b, h; bhmap(b, h);
    const int tid = threadIdx.x;
    __shared__ __align__(16) ushort T[128 * 136];   // [w][c], pad 8
    const int w0 = tid & 127, cg = tid >> 7;
#pragma unroll 4
    for (int it = 0; it < 64; it++) {
        int c = it * 2 + cg;
        float f = x[((size_t)(b * 128 + c)) * HW + h * 128 + w0];
        T[w0 * 136 + c] = f2bf(f);
    }
    __syncthreads();
    const int w1 = tid >> 1, half = tid & 1;
    uint4* dst = (uint4*)(xt + (((size_t)b * HW) + h * 128 + w1) * 128 + half * 64);
    const uint4* src = (const uint4*)&T[w1 * 136 + half * 64];
#pragma unroll
    for (int c8 = 0; c8 < 8; c8++) dst[c8] = src[c8];
}

// ---------------------------------------------------------------------------
// k_om v10 (verified R10): per-dy As[130][128] staging, Bs[3] taps via
// gl2lds, 6 barriers. (unchanged)
// ---------------------------------------------------------------------------
__global__ __launch_bounds__(512, 4) void k_om(
    const ushort* __restrict__ xt, const float* __restrict__ U,
    const ushort* __restrict__ womt, const float* __restrict__ womu,
    const float* __restrict__ bom, float* __restrict__ omt)
{
    int b, h; bhmap(b, h);
    const int tid = threadIdx.x;
    const int wid = tid >> 6, lane = tid & 63, lq = lane & 15, quad = lane >> 4;
    const int pixbase = wid * 16;

    __shared__ __align__(16) ushort As[130 * 128];   // 33.3 KB
    __shared__ __align__(16) ushort Bs[3][32 * 128]; // 24 KB
    __shared__ float U3[3 * 130];
    __shared__ float wu[288];

    f32x4 acc[2];
#pragma unroll
    for (int j = 0; j < 2; j++)
#pragma unroll
        for (int r = 0; r < 4; r++) acc[j][r] = 0.f;

    for (int s = tid; s < 390; s += 512) {
        int r = s / 130, c = s % 130, gy = h - 1 + r, gx = c - 1;
        float v = 0.f;
        if ((unsigned)gy < 128u && (unsigned)gx < 128u) {
            v = U[(size_t)b * HW + gy * 128 + gx];
            v = fminf(fmaxf(v, 0.f), 1.f);
        }
        U3[s] = v;
    }
    if (tid < 288) wu[tid] = womu[tid];

    const size_t xb = (size_t)b * HW * 128;
#pragma unroll
    for (int dyi = 0; dyi < 3; dyi++) {
        int gy = h + dyi - 1;
        // As: 130 rows x 16 chunks = 2080 16B-chunks over 512 threads
        for (int c = tid; c < 2080; c += 512) {
            int r = c >> 4, ch = c & 15, gx = r - 1;
            uint4 v = {0, 0, 0, 0};
            if ((unsigned)gy < 128u && (unsigned)gx < 128u)
                v = *(const uint4*)(xt + xb + ((size_t)gy * 128 + gx) * 128 + ch * 8);
            *(uint4*)&As[swz(r, ch)] = v;
        }
        // Bs: 3 taps of this dy, async 16B/lane each (pre-swizzled womt)
#pragma unroll
        for (int t = 0; t < 3; t++)
            gl2lds16(womt + (dyi * 3 + t) * 4096 + tid * 8, &Bs[t][wid * 512]);
        __syncthreads();
#pragma unroll
        for (int dx = 0; dx < 3; dx++) {
#pragma unroll
            for (int kk = 0; kk < 4; kk++) {
                int chunk = kk * 4 + quad;
                bf16x8 av = *(const bf16x8*)&As[swz(pixbase + lq + dx, chunk)];
                bf16x8 bv[2];
#pragma unroll
                for (int j = 0; j < 2; j++) bv[j] = *(const bf16x8*)&Bs[dx][swz(j * 16 + lq, chunk)];
#pragma unroll
                for (int j = 0; j < 2; j++)
                    acc[j] = __builtin_amdgcn_mfma_f32_16x16x32_bf16(av, bv[j], acc[j], 0, 0, 0);
            }
        }
        __syncthreads();
    }

    // epilogue: + bias + U-channel conv term; sigmoid for mask channels
#pragma unroll
    for (int j = 0; j < 2; j++) {
        int oc = j * 16 + lq;
        if (oc < 27) {
            float bias = bom[oc];
#pragma unroll
            for (int r = 0; r < 4; r++) {
                int pix = pixbase + quad * 4 + r;
                float v = acc[j][r] + bias;
#pragma unroll
                for (int t = 0; t < 9; t++)
                    v += U3[(t / 3) * 130 + pix + (t % 3)] * wu[t * 32 + oc];
                if (oc >= 18) v = 2.f / (1.f + __expf(-v));
                omt[((size_t)b * HW + h * 128 + pix) * 32 + oc] = v;
            }
        }
    }
}

// ---------------------------------------------------------------------------
// k_dcn: round-6 verified version (51.2 us). 128-pixel blocks (grid 512),
// 8 waves, wave tile 64 pix x 32 oc, two barriers/tap, dbuf corner table
// built during MFMA, Bs via async global_load_lds (pre-swizzled wdt),
// blend2 v5. (unchanged)
// ---------------------------------------------------------------------------
__global__ __launch_bounds__(512, 4) void k_dcn(
    const ushort* __restrict__ xt, const float* __restrict__ omt,
    const ushort* __restrict__ wdt, const float* __restrict__ bdcn,
    ushort* __restrict__ zt)
{
    int b, h; bhmap(b, h);
    const int tid = threadIdx.x;
    const int wid = tid >> 6, lane = tid & 63, lq = lane & 15, quad = lane >> 4;
    const int pixbase = (wid & 1) * 64, ocbase = (wid >> 1) * 32;

    __shared__ __align__(16) ushort As[128 * 128];   // 32 KB
    __shared__ __align__(16) ushort Bs[128 * 128];   // 32 KB
    __shared__ __align__(16) int tbl[2][128][8];     // 8 KB

    const int sc = lane & 15;        // channel chunk
    const int sp = lane >> 4;        // pixel slot

    f32x4 acc[4][2];
#pragma unroll
    for (int i = 0; i < 4; i++)
#pragma unroll
        for (int j = 0; j < 2; j++)
#pragma unroll
            for (int r = 0; r < 4; r++) acc[i][j][r] = 0.f;

    const float* omrow = omt + ((size_t)b * HW + h * 128) * 32;
    const ushort* xtb = xt + (size_t)b * HW * 128;

    auto build = [&](int k, int buf) {
        if (tid < 128) {
            int p = tid;
            float dyv = omrow[p * 32 + 2 * k];
            float dxv = omrow[p * 32 + 2 * k + 1];
            float m   = omrow[p * 32 + 18 + k];
            float fy = (float)(h + k / 3 - 1) + dyv;
            float fx = (float)(p + k % 3 - 1) + dxv;
            float y0f = floorf(fy), x0f = floorf(fx);
            float ly = fy - y0f, lx = fx - x0f;
            float hy = 1.f - ly, hx = 1.f - lx;
            bool vy0 = (y0f >= 0.f) && (y0f <= 127.f);
            bool vy1 = (y0f >= -1.f) && (y0f <= 126.f);
            bool vx0 = (x0f >= 0.f) && (x0f <= 127.f);
            bool vx1 = (x0f >= -1.f) && (x0f <= 126.f);
            float w00 = (vy0 && vx0) ? hy * hx * m : 0.f;
            float w01 = (vy0 && vx1) ? hy * lx * m : 0.f;
            float w10 = (vy1 && vx0) ? ly * hx * m : 0.f;
            float w11 = (vy1 && vx1) ? ly * lx * m : 0.f;
            int iy0 = min(max((int)y0f, 0), 127);
            int iy1 = min(max((int)y0f + 1, 0), 127);
            int ix0 = min(max((int)x0f, 0), 127);
            int ix1 = min(max((int)x0f + 1, 0), 127);
            int* tp = &tbl[buf][p][0];
            tp[0] = (iy0 * 128 + ix0) * 128;
            tp[1] = (iy0 * 128 + ix1) * 128;
            tp[2] = (iy1 * 128 + ix0) * 128;
            tp[3] = (iy1 * 128 + ix1) * 128;
            ((float*)tp)[4] = w00; ((float*)tp)[5] = w01;
            ((float*)tp)[6] = w10; ((float*)tp)[7] = w11;
        }
    };

    build(0, 0);
    __syncthreads();

    for (int k = 0; k < 9; k++) {
        const int buf = k & 1;
        // Bs: 4 async 16B/lane from pre-swizzled wdt (issued first; overlap
        // with the gather phase below; drained by the barrier)
        {
            const ushort* wsrc = wdt + (size_t)k * 16384;
#pragma unroll
            for (int c = 0; c < 4; c++)
                gl2lds16(wsrc + c * 4096 + tid * 8, &Bs[c * 4096 + wid * 512]);
        }
        // A: 4 rounds, 4 pixels per wave per round, 16 lanes span one corner row
        const ushort* basep = xtb + sc * 8;
#pragma unroll 2
        for (int r = 0; r < 4; r++) {
            int p = r * 32 + wid * 4 + sp;
            int4 off = *(const int4*)&tbl[buf][p][0];
            f32x4 wv = *(const f32x4*)((const float*)&tbl[buf][p][0] + 4);
            uint4 q00 = *(const uint4*)(basep + off.x);
            uint4 q01 = *(const uint4*)(basep + off.y);
            uint4 q10 = *(const uint4*)(basep + off.z);
            uint4 q11 = *(const uint4*)(basep + off.w);
            uint4 st;
            st.x = blend2(q00.x, q01.x, q10.x, q11.x, wv[0], wv[1], wv[2], wv[3]);
            st.y = blend2(q00.y, q01.y, q10.y, q11.y, wv[0], wv[1], wv[2], wv[3]);
            st.z = blend2(q00.z, q01.z, q10.z, q11.z, wv[0], wv[1], wv[2], wv[3]);
            st.w = blend2(q00.w, q01.w, q10.w, q11.w, wv[0], wv[1], wv[2], wv[3]);
            *(uint4*)&As[swz(p, sc)] = st;
        }
        __syncthreads();
        if (k < 8) build(k + 1, buf ^ 1);      // hides behind MFMA
#pragma unroll
        for (int kk = 0; kk < 4; kk++) {
            int chunk = kk * 4 + quad;
            bf16x8 av[4], bv[2];
#pragma unroll
            for (int i = 0; i < 4; i++) av[i] = *(const bf16x8*)&As[swz(pixbase + i * 16 + lq, chunk)];
#pragma unroll
            for (int j = 0; j < 2; j++) bv[j] = *(const bf16x8*)&Bs[swz(ocbase + j * 16 + lq, chunk)];
#pragma unroll
            for (int i = 0; i < 4; i++)
#pragma unroll
                for (int j = 0; j < 2; j++)
                    acc[i][j] = __builtin_amdgcn_mfma_f32_16x16x32_bf16(av[i], bv[j], acc[i][j], 0, 0, 0);
        }
        __syncthreads();
    }

    size_t prow = ((size_t)b * HW + h * 128) * 128;
#pragma unroll
    for (int j = 0; j < 2; j++) {
        int oc = ocbase + j * 16 + lq;
        float bias = bdcn[oc];
#pragma unroll
        for (int i = 0; i < 4; i++)
#pragma unroll
            for (int r = 0; r < 4; r++) {
                int pix = pixbase + i * 16 + quad * 4 + r;
                zt[prow + (size_t)pix * 128 + oc] = f2bf(acc[i][j][r] + bias);
            }
    }
}

// ---------------------------------------------------------------------------
// k_conv1 v11: r1 = relu(conv3x3(z) + b1), NHWC bf16. Round-6 barrier
// structure (2/tap) with the R10-proven per-dy transform applied to the
// ACTIVATION tile only: As[130][128] (zt halo row) staged once per dy under
// if(dx==0); MFMA reads row pix+dx (invariant As[r] <- z[gx=r-1]; max row
// 129 < 130). Weights stay per-tap gl2lds into Bs (R2/R9: regs refuted).
// LDS 33.3+32 = 65.3 KB -> 2 blocks/CU. Activation staging 9 -> 3.
// ---------------------------------------------------------------------------
__global__ __launch_bounds__(512, 4) void k_conv1(
    const ushort* __restrict__ zt, const ushort* __restrict__ w1t,
    const float* __restrict__ b1, ushort* __restrict__ r1t)
{
    int b, h; bhmap(b, h);
    const int tid = threadIdx.x;
    const int wid = tid >> 6, lane = tid & 63, lq = lane & 15, quad = lane >> 4;
    const int pixbase = (wid & 1) * 64, ocbase = (wid >> 1) * 32;

    __shared__ __align__(16) ushort As[130 * 128];   // activations, 33.3 KB
    __shared__ __align__(16) ushort Bs[128 * 128];   // weights, 32 KB

    f32x4 acc[4][2];
#pragma unroll
    for (int i = 0; i < 4; i++)
#pragma unroll
        for (int j = 0; j < 2; j++)
#pragma unroll
            for (int r = 0; r < 4; r++) acc[i][j][r] = 0.f;

    const size_t zb = (size_t)b * HW * 128;
    for (int t9 = 0; t9 < 9; t9++) {
        const int dyi = t9 / 3, dx = t9 % 3;
        if (dx == 0) {                      // stage zt halo row once per dy
            int gy = h + dyi - 1;
            for (int c = tid; c < 2080; c += 512) {
                int r = c >> 4, ch = c & 15, gx = r - 1;
                uint4 v = {0, 0, 0, 0};
                if ((unsigned)gy < 128u && (unsigned)gx < 128u)
                    v = *(const uint4*)(zt + zb + ((size_t)gy * 128 + gx) * 128 + ch * 8);
                *(uint4*)&As[swz(r, ch)] = v;
            }
        }
        // Bs: async 16B/lane x4 from pre-swizzled w1t
        {
            const ushort* wsrc = w1t + (size_t)t9 * 16384;
#pragma unroll
            for (int c = 0; c < 4; c++)
                gl2lds16(wsrc + c * 4096 + tid * 8, &Bs[c * 4096 + wid * 512]);
        }
        __syncthreads();
#pragma unroll
        for (int kk = 0; kk < 4; kk++) {
            int chunk = kk * 4 + quad;
            bf16x8 av[4], bv[2];
#pragma unroll
            for (int i = 0; i < 4; i++)
                av[i] = *(const bf16x8*)&As[swz(pixbase + i * 16 + lq + dx, chunk)];
#pragma unroll
            for (int j = 0; j < 2; j++) bv[j] = *(const bf16x8*)&Bs[swz(ocbase + j * 16 + lq, chunk)];
#pragma unroll
            for (int i = 0; i < 4; i++)
#pragma unroll
                for (int j = 0; j < 2; j++)
                    acc[i][j] = __builtin_amdgcn_mfma_f32_16x16x32_bf16(av[i], bv[j], acc[i][j], 0, 0, 0);
        }
        __syncthreads();
    }

    size_t prow = ((size_t)b * HW + h * 128) * 128;
#pragma unroll
    for (int j = 0; j < 2; j++) {
        int oc = ocbase + j * 16 + lq;
        float bias = b1[oc];
#pragma unroll
        for (int i = 0; i < 4; i++)
#pragma unroll
            for (int r = 0; r < 4; r++) {
                int pix = pixbase + i * 16 + quad * 4 + r;
                r1t[prow + (size_t)pix * 128 + oc] = f2bf(fmaxf(acc[i][j][r] + bias, 0.f));
            }
    }
}

// ---------------------------------------------------------------------------
// k_conv2 v11: out = relu(x + (conv3x3(r1)+b2) * sigmoid(10*(clipU-0.5))).
// M=oc (weights As via per-tap gl2lds), N=pix. Per-dy transform on the
// ACTIVATION tile: Bs[130][128] (r1t halo row) staged once per dy under
// if(dx==0); MFMA reads row nbase+j*16+lq+dx (max 129 < 130).
// LDS 32+33.3 = 65.3 KB -> 2 blocks/CU. Activation staging 9 -> 3.
// ---------------------------------------------------------------------------
__global__ __launch_bounds__(512, 4) void k_conv2(
    const ushort* __restrict__ r1t, const ushort* __restrict__ w2t,
    const float* __restrict__ b2, const float* __restrict__ x,
    const float* __restrict__ U, float* __restrict__ out)
{
    int b, h; bhmap(b, h);
    const int tid = threadIdx.x;
    const int wid = tid >> 6, lane = tid & 63, lq = lane & 15, quad = lane >> 4;
    const int mbase = (wid & 1) * 64;   // oc
    const int nbase = (wid >> 1) * 32;  // pix

    __shared__ __align__(16) ushort As[128 * 128];  // weights  [oc][ci], 32 KB
    __shared__ __align__(16) ushort Bs[130 * 128];  // activ. halo, 33.3 KB

    f32x4 acc[4][2];
#pragma unroll
    for (int i = 0; i < 4; i++)
#pragma unroll
        for (int j = 0; j < 2; j++)
#pragma unroll
            for (int r = 0; r < 4; r++) acc[i][j][r] = 0.f;

    const size_t rb = (size_t)b * HW * 128;
    for (int t9 = 0; t9 < 9; t9++) {
        const int dyi = t9 / 3, dx = t9 % 3;
        if (dx == 0) {                      // stage r1t halo row once per dy
            int gy = h + dyi - 1;
            for (int c = tid; c < 2080; c += 512) {
                int r = c >> 4, ch = c & 15, gx = r - 1;
                uint4 v = {0, 0, 0, 0};
                if ((unsigned)gy < 128u && (unsigned)gx < 128u)
                    v = *(const uint4*)(r1t + rb + ((size_t)gy * 128 + gx) * 128 + ch * 8);
                *(uint4*)&Bs[swz(r, ch)] = v;
            }
        }
        // As (weights): async 16B/lane x4 from pre-swizzled w2t
        {
            const ushort* wsrc = w2t + (size_t)t9 * 16384;
#pragma unroll
            for (int c = 0; c < 4; c++)
                gl2lds16(wsrc + c * 4096 + tid * 8, &As[c * 4096 + wid * 512]);
        }
        __syncthreads();
#pragma unroll
        for (int kk = 0; kk < 4; kk++) {
            int chunk = kk * 4 + quad;
            bf16x8 av[4], bv[2];
#pragma unroll
            for (int i = 0; i < 4; i++) av[i] = *(const bf16x8*)&As[swz(mbase + i * 16 + lq, chunk)];
#pragma unroll
            for (int j = 0; j < 2; j++)
                bv[j] = *(const bf16x8*)&Bs[swz(nbase + j * 16 + lq + dx, chunk)];
#pragma unroll
            for (int i = 0; i < 4; i++)
#pragma unroll
                for (int j = 0; j < 2; j++)
                    acc[i][j] = __builtin_amdgcn_mfma_f32_16x16x32_bf16(av[i], bv[j], acc[i][j], 0, 0, 0);
        }
        __syncthreads();
    }

#pragma unroll
    for (int j = 0; j < 2; j++) {
        int pix = nbase + j * 16 + lq;
        float u = U[(size_t)b * HW + h * 128 + pix];
        u = fminf(fmaxf(u, 0.f), 1.f);
        float g = 1.f / (1.f + __expf(-10.f * (u - 0.5f)));
#pragma unroll
        for (int i = 0; i < 4; i++) {
            f32x4 b4 = *(const f32x4*)&b2[mbase + i * 16 + quad * 4];
#pragma unroll
            for (int r = 0; r < 4; r++) {
                int oc = mbase + i * 16 + quad * 4 + r;
                size_t idx = ((size_t)(b * 128 + oc)) * HW + h * 128 + pix;
                float v = acc[i][j][r] + b4[r];
                out[idx] = fmaxf(x[idx] + v * g, 0.f);
            }
        }
    }
}

// ---------------------------------------------------------------------------
extern "C" void kernel_launch(void* const* d_in, const int* in_sizes, int n_in,
                              void* d_out, int out_size, void* d_ws, size_t ws_size,
                              hipStream_t stream)
{
    const float* x     = (const float*)d_in[0];
    const float* U     = (const float*)d_in[1];
    const float* w_om  = (const float*)d_in[2];
    const float* b_om  = (const float*)d_in[3];
    const float* w_dcn = (const float*)d_in[4];
    const float* b_dcn = (const float*)d_in[5];
    const float* w1    = (const float*)d_in[6];
    const float* b1    = (const float*)d_in[7];
    const float* w2    = (const float*)d_in[8];
    const float* b2    = (const float*)d_in[9];
    float* out = (float*)d_out;

    char* p = (char*)d_ws;
    ushort* xt   = (ushort*)p; p += (size_t)4 * HW * 128 * 2;   // 16.78 MB
    ushort* zt   = (ushort*)p; p += (size_t)4 * HW * 128 * 2;
    ushort* r1t  = (ushort*)p; p += (size_t)4 * HW * 128 * 2;
    float*  omt  = (float*)p;  p += (size_t)4 * HW * 32 * 4;    // 8.39 MB
    ushort* wdt  = (ushort*)p; p += 147456 * 2;
    ushort* w1t  = (ushort*)p; p += 147456 * 2;
    ushort* w2t  = (ushort*)p; p += 147456 * 2;
    ushort* womt = (ushort*)p; p += 36864 * 2;
    float*  womu = (float*)p;  p += 288 * 4;

    prep_w<<<576, 256, 0, stream>>>(w_dcn, w1, w2, w_om, wdt, w1t, w2t, womt, womu);
    prep_xt<<<dim3(128, 4), 256, 0, stream>>>(x, xt);
    k_om<<<dim3(128, 4), 512, 0, stream>>>(xt, U, womt, womu, b_om, omt);
    k_dcn<<<dim3(128, 4), 512, 0, stream>>>(xt, omt, wdt, b_dcn, zt);
    k_conv1<<<dim3(128, 4), 512, 0, stream>>>(zt, w1t, b1, r1t);
    k_conv2<<<dim3(128, 4), 512, 0, stream>>>(r1t, w2t, b2, x, U, out);
}

// Round 13
// 215.925 us; speedup vs baseline: 1.0577x; 1.0002x over previous
//
#include <hip/hip_runtime.h>
#include <math.h>

typedef unsigned int uint;
typedef unsigned short ushort;
typedef __attribute__((ext_vector_type(8))) __bf16 bf16x8;
typedef __attribute__((ext_vector_type(2))) __bf16 bf16x2;
typedef __attribute__((ext_vector_type(4))) float f32x4;
typedef __attribute__((ext_vector_type(2))) float f32x2;

#define HW 16384   // 128*128

// ---------- helpers ----------
__device__ __forceinline__ ushort f2bf(float f) {          // fp32 -> bf16 RNE
    uint u = __float_as_uint(f);
    u += 0x7fffu + ((u >> 16) & 1u);
    return (ushort)(u >> 16);
}
// XCD-affinity swizzle: 512 blocks; remap so XCD k owns 64 contiguous (b,h)
// rows -> per-XCD L2 working set < 4 MB; producers/consumers share mapping.
__device__ __forceinline__ void bhmap(int& b, int& h) {
    int lin = blockIdx.y * (int)gridDim.x + blockIdx.x;
    int n = (lin & 7) * 64 + (lin >> 3);
    h = n & 127;
    b = n >> 7;
}
// 256-block variant (2 output rows per block): same per-XCD (b,h) ownership.
__device__ __forceinline__ void bhmap2r(int& b, int& h0) {
    int lin = blockIdx.y * (int)gridDim.x + blockIdx.x;
    int n = (lin & 7) * 32 + (lin >> 3);
    h0 = (n & 63) * 2;
    b = n >> 6;
}
// swizzled element index into a [rows][128] bf16 LDS tile.
__device__ __forceinline__ int swz(int row, int chunk) {
    return row * 128 + ((chunk ^ (row & 15)) << 3);
}
// async 16B global -> LDS (linear dest: wave-uniform base + lane*16).
// Weight buffers are stored PRE-SWIZZLED in global (prep_w), so linear
// loads produce the same LDS contents the old reg-staged swizzled writes
// did -> MFMA reads (via swz) are bit-identical.
__device__ __forceinline__ void gl2lds16(const ushort* g, ushort* l) {
    __builtin_amdgcn_global_load_lds(
        (const __attribute__((address_space(1))) uint*)g,
        (__attribute__((address_space(3))) uint*)l,
        16, 0, 0);
}
// bilinear blend of 4 packed bf16 pairs -> packed bf16 pair.
// v5 body (bit-identical to manual RNE, verified R5/R6: absmax 0.03125):
// packed f32x2 arith (v_pk_mul/v_pk_fma) + compiler bf16 casts for the pack.
__device__ __forceinline__ uint blend2(uint a, uint b, uint c, uint d,
                                       float w00, float w01, float w10, float w11) {
    f32x2 va = { __uint_as_float(a << 16), __uint_as_float(a & 0xffff0000u) };
    f32x2 vb = { __uint_as_float(b << 16), __uint_as_float(b & 0xffff0000u) };
    f32x2 vc = { __uint_as_float(c << 16), __uint_as_float(c & 0xffff0000u) };
    f32x2 vd = { __uint_as_float(d << 16), __uint_as_float(d & 0xffff0000u) };
    f32x2 v = va * w00 + vb * w01 + vc * w10 + vd * w11;
    bf16x2 pk; pk[0] = (__bf16)v[0]; pk[1] = (__bf16)v[1];
    uint r; __builtin_memcpy(&r, &pk, 4);
    return r;
}

// ---------------------------------------------------------------------------
// Prep 1: weights -> bf16, PRE-SWIZZLED [tap][row][d] where element d of a
// row holds source ci = ((d>>3) ^ (row&15))*8 + (d&7). A linear global->LDS
// copy then reproduces the swizzled LDS tile the GEMM kernels read via swz().
// ---------------------------------------------------------------------------
__global__ __launch_bounds__(256) void prep_w(
    const float* __restrict__ wd, const float* __restrict__ w1,
    const float* __restrict__ w2, const float* __restrict__ wom,
    ushort* __restrict__ wdt, ushort* __restrict__ w1t,
    ushort* __restrict__ w2t, ushort* __restrict__ womt,
    float* __restrict__ womu)
{
    int i = blockIdx.x * 256 + threadIdx.x;
    if (i < 147456) {                       // [k][oc][d], 9*128*128
        int k = i >> 14, oc = (i >> 7) & 127, d = i & 127;
        int ci = (((d >> 3) ^ (oc & 15)) << 3) | (d & 7);
        int s = (oc * 128 + ci) * 9 + k;
        wdt[i] = f2bf(wd[s]);
        w1t[i] = f2bf(w1[s]);
        w2t[i] = f2bf(w2[s]);
    }
    if (i < 36864) {                        // [k][32][128]
        int k = i >> 12, oc = (i >> 7) & 31, d = i & 127;
        int ci = (((d >> 3) ^ (oc & 15)) << 3) | (d & 7);
        womt[i] = (oc < 27) ? f2bf(wom[(oc * 129 + ci) * 9 + k]) : (ushort)0;
    }
    if (i < 288) {                          // U-channel column: [k][32]
        int k = i >> 5, oc = i & 31;
        womu[i] = (oc < 27) ? wom[(oc * 129 + 128) * 9 + k] : 0.f;
    }
}

// ---------------------------------------------------------------------------
// Prep 2: x NCHW fp32 -> x_t NHWC bf16, LDS-transposed per (b,h) row.
// ---------------------------------------------------------------------------
__global__ __launch_bounds__(256) void prep_xt(
    const float* __restrict__ x, ushort* __restrict__ xt)
{
    int b, h; bhmap(b, h);
    const int tid = threadIdx.x;
    __shared__ __align__(16) ushort T[128 * 136];   // [w][c], pad 8
    const int w0 = tid & 127, cg = tid >> 7;
#pragma unroll 4
    for (int it = 0; it < 64; it++) {
        int c = it * 2 + cg;
        float f = x[((size_t)(b * 128 + c)) * HW + h * 128 + w0];
        T[w0 * 136 + c] = f2bf(f);
    }
    __syncthreads();
    const int w1 = tid >> 1, half = tid & 1;
    uint4* dst = (uint4*)(xt + (((size_t)b * HW) + h * 128 + w1) * 128 + half * 64);
    const uint4* src = (const uint4*)&T[w1 * 136 + half * 64];
#pragma unroll
    for (int c8 = 0; c8 < 8; c8++) dst[c8] = src[c8];
}

// ---------------------------------------------------------------------------
// k_om v10 (verified R10): per-dy As[130][128] staging, Bs[3] taps via
// gl2lds, 6 barriers. (unchanged)
// ---------------------------------------------------------------------------
__global__ __launch_bounds__(512, 4) void k_om(
    const ushort* __restrict__ xt, const float* __restrict__ U,
    const ushort* __restrict__ womt, const float* __restrict__ womu,
    const float* __restrict__ bom, float* __restrict__ omt)
{
    int b, h; bhmap(b, h);
    const int tid = threadIdx.x;
    const int wid = tid >> 6, lane = tid & 63, lq = lane & 15, quad = lane >> 4;
    const int pixbase = wid * 16;

    __shared__ __align__(16) ushort As[130 * 128];   // 33.3 KB
    __shared__ __align__(16) ushort Bs[3][32 * 128]; // 24 KB
    __shared__ float U3[3 * 130];
    __shared__ float wu[288];

    f32x4 acc[2];
#pragma unroll
    for (int j = 0; j < 2; j++)
#pragma unroll
        for (int r = 0; r < 4; r++) acc[j][r] = 0.f;

    for (int s = tid; s < 390; s += 512) {
        int r = s / 130, c = s % 130, gy = h - 1 + r, gx = c - 1;
        float v = 0.f;
        if ((unsigned)gy < 128u && (unsigned)gx < 128u) {
            v = U[(size_t)b * HW + gy * 128 + gx];
            v = fminf(fmaxf(v, 0.f), 1.f);
        }
        U3[s] = v;
    }
    if (tid < 288) wu[tid] = womu[tid];

    const size_t xb = (size_t)b * HW * 128;
#pragma unroll
    for (int dyi = 0; dyi < 3; dyi++) {
        int gy = h + dyi - 1;
        // As: 130 rows x 16 chunks = 2080 16B-chunks over 512 threads
        for (int c = tid; c < 2080; c += 512) {
            int r = c >> 4, ch = c & 15, gx = r - 1;
            uint4 v = {0, 0, 0, 0};
            if ((unsigned)gy < 128u && (unsigned)gx < 128u)
                v = *(const uint4*)(xt + xb + ((size_t)gy * 128 + gx) * 128 + ch * 8);
            *(uint4*)&As[swz(r, ch)] = v;
        }
        // Bs: 3 taps of this dy, async 16B/lane each (pre-swizzled womt)
#pragma unroll
        for (int t = 0; t < 3; t++)
            gl2lds16(womt + (dyi * 3 + t) * 4096 + tid * 8, &Bs[t][wid * 512]);
        __syncthreads();
#pragma unroll
        for (int dx = 0; dx < 3; dx++) {
#pragma unroll
            for (int kk = 0; kk < 4; kk++) {
                int chunk = kk * 4 + quad;
                bf16x8 av = *(const bf16x8*)&As[swz(pixbase + lq + dx, chunk)];
                bf16x8 bv[2];
#pragma unroll
                for (int j = 0; j < 2; j++) bv[j] = *(const bf16x8*)&Bs[dx][swz(j * 16 + lq, chunk)];
#pragma unroll
                for (int j = 0; j < 2; j++)
                    acc[j] = __builtin_amdgcn_mfma_f32_16x16x32_bf16(av, bv[j], acc[j], 0, 0, 0);
            }
        }
        __syncthreads();
    }

    // epilogue: + bias + U-channel conv term; sigmoid for mask channels
#pragma unroll
    for (int j = 0; j < 2; j++) {
        int oc = j * 16 + lq;
        if (oc < 27) {
            float bias = bom[oc];
#pragma unroll
            for (int r = 0; r < 4; r++) {
                int pix = pixbase + quad * 4 + r;
                float v = acc[j][r] + bias;
#pragma unroll
                for (int t = 0; t < 9; t++)
                    v += U3[(t / 3) * 130 + pix + (t % 3)] * wu[t * 32 + oc];
                if (oc >= 18) v = 2.f / (1.f + __expf(-v));
                omt[((size_t)b * HW + h * 128 + pix) * 32 + oc] = v;
            }
        }
    }
}

// ---------------------------------------------------------------------------
// k_dcn: round-6 verified version. 128-pixel blocks (grid 512), 8 waves,
// wave tile 64 pix x 32 oc, two barriers/tap, dbuf corner table built
// during MFMA, Bs via async global_load_lds (pre-swizzled wdt), blend2 v5.
// (unchanged)
// ---------------------------------------------------------------------------
__global__ __launch_bounds__(512, 4) void k_dcn(
    const ushort* __restrict__ xt, const float* __restrict__ omt,
    const ushort* __restrict__ wdt, const float* __restrict__ bdcn,
    ushort* __restrict__ zt)
{
    int b, h; bhmap(b, h);
    const int tid = threadIdx.x;
    const int wid = tid >> 6, lane = tid & 63, lq = lane & 15, quad = lane >> 4;
    const int pixbase = (wid & 1) * 64, ocbase = (wid >> 1) * 32;

    __shared__ __align__(16) ushort As[128 * 128];   // 32 KB
    __shared__ __align__(16) ushort Bs[128 * 128];   // 32 KB
    __shared__ __align__(16) int tbl[2][128][8];     // 8 KB

    const int sc = lane & 15;        // channel chunk
    const int sp = lane >> 4;        // pixel slot

    f32x4 acc[4][2];
#pragma unroll
    for (int i = 0; i < 4; i++)
#pragma unroll
        for (int j = 0; j < 2; j++)
#pragma unroll
            for (int r = 0; r < 4; r++) acc[i][j][r] = 0.f;

    const float* omrow = omt + ((size_t)b * HW + h * 128) * 32;
    const ushort* xtb = xt + (size_t)b * HW * 128;

    auto build = [&](int k, int buf) {
        if (tid < 128) {
            int p = tid;
            float dyv = omrow[p * 32 + 2 * k];
            float dxv = omrow[p * 32 + 2 * k + 1];
            float m   = omrow[p * 32 + 18 + k];
            float fy = (float)(h + k / 3 - 1) + dyv;
            float fx = (float)(p + k % 3 - 1) + dxv;
            float y0f = floorf(fy), x0f = floorf(fx);
            float ly = fy - y0f, lx = fx - x0f;
            float hy = 1.f - ly, hx = 1.f - lx;
            bool vy0 = (y0f >= 0.f) && (y0f <= 127.f);
            bool vy1 = (y0f >= -1.f) && (y0f <= 126.f);
            bool vx0 = (x0f >= 0.f) && (x0f <= 127.f);
            bool vx1 = (x0f >= -1.f) && (x0f <= 126.f);
            float w00 = (vy0 && vx0) ? hy * hx * m : 0.f;
            float w01 = (vy0 && vx1) ? hy * lx * m : 0.f;
            float w10 = (vy1 && vx0) ? ly * hx * m : 0.f;
            float w11 = (vy1 && vx1) ? ly * lx * m : 0.f;
            int iy0 = min(max((int)y0f, 0), 127);
            int iy1 = min(max((int)y0f + 1, 0), 127);
            int ix0 = min(max((int)x0f, 0), 127);
            int ix1 = min(max((int)x0f + 1, 0), 127);
            int* tp = &tbl[buf][p][0];
            tp[0] = (iy0 * 128 + ix0) * 128;
            tp[1] = (iy0 * 128 + ix1) * 128;
            tp[2] = (iy1 * 128 + ix0) * 128;
            tp[3] = (iy1 * 128 + ix1) * 128;
            ((float*)tp)[4] = w00; ((float*)tp)[5] = w01;
            ((float*)tp)[6] = w10; ((float*)tp)[7] = w11;
        }
    };

    build(0, 0);
    __syncthreads();

    for (int k = 0; k < 9; k++) {
        const int buf = k & 1;
        // Bs: 4 async 16B/lane from pre-swizzled wdt (issued first; overlap
        // with the gather phase below; drained by the barrier)
        {
            const ushort* wsrc = wdt + (size_t)k * 16384;
#pragma unroll
            for (int c = 0; c < 4; c++)
                gl2lds16(wsrc + c * 4096 + tid * 8, &Bs[c * 4096 + wid * 512]);
        }
        // A: 4 rounds, 4 pixels per wave per round, 16 lanes span one corner row
        const ushort* basep = xtb + sc * 8;
#pragma unroll 2
        for (int r = 0; r < 4; r++) {
            int p = r * 32 + wid * 4 + sp;
            int4 off = *(const int4*)&tbl[buf][p][0];
            f32x4 wv = *(const f32x4*)((const float*)&tbl[buf][p][0] + 4);
            uint4 q00 = *(const uint4*)(basep + off.x);
            uint4 q01 = *(const uint4*)(basep + off.y);
            uint4 q10 = *(const uint4*)(basep + off.z);
            uint4 q11 = *(const uint4*)(basep + off.w);
            uint4 st;
            st.x = blend2(q00.x, q01.x, q10.x, q11.x, wv[0], wv[1], wv[2], wv[3]);
            st.y = blend2(q00.y, q01.y, q10.y, q11.y, wv[0], wv[1], wv[2], wv[3]);
            st.z = blend2(q00.z, q01.z, q10.z, q11.z, wv[0], wv[1], wv[2], wv[3]);
            st.w = blend2(q00.w, q01.w, q10.w, q11.w, wv[0], wv[1], wv[2], wv[3]);
            *(uint4*)&As[swz(p, sc)] = st;
        }
        __syncthreads();
        if (k < 8) build(k + 1, buf ^ 1);      // hides behind MFMA
#pragma unroll
        for (int kk = 0; kk < 4; kk++) {
            int chunk = kk * 4 + quad;
            bf16x8 av[4], bv[2];
#pragma unroll
            for (int i = 0; i < 4; i++) av[i] = *(const bf16x8*)&As[swz(pixbase + i * 16 + lq, chunk)];
#pragma unroll
            for (int j = 0; j < 2; j++) bv[j] = *(const bf16x8*)&Bs[swz(ocbase + j * 16 + lq, chunk)];
#pragma unroll
            for (int i = 0; i < 4; i++)
#pragma unroll
                for (int j = 0; j < 2; j++)
                    acc[i][j] = __builtin_amdgcn_mfma_f32_16x16x32_bf16(av[i], bv[j], acc[i][j], 0, 0, 0);
        }
        __syncthreads();
    }

    size_t prow = ((size_t)b * HW + h * 128) * 128;
#pragma unroll
    for (int j = 0; j < 2; j++) {
        int oc = ocbase + j * 16 + lq;
        float bias = bdcn[oc];
#pragma unroll
        for (int i = 0; i < 4; i++)
#pragma unroll
            for (int r = 0; r < 4; r++) {
                int pix = pixbase + i * 16 + quad * 4 + r;
                zt[prow + (size_t)pix * 128 + oc] = f2bf(acc[i][j][r] + bias);
            }
    }
}

// ---------------------------------------------------------------------------
// k_conv1 v12: r1 = relu(conv3x3(z) + b1). 1024 thr, 16 waves, 2 output
// rows per block (grid 256). Halves per-output weight staging AND barrier
// count (the R11-null showed activation staging is NOT the binding cost —
// weights+barriers are). Wave map: bit3=row, bit0=pix-half, bits1-2=oc-grp.
// As[2][130][128] activation halo per dy (66.6 KB); Bs weights 32 KB via
// gl2lds (2/thread). LDS 98.6 KB -> 1 block/CU, 16 waves (same wave count
// as 2x8 before). Per-output math bit-identical.
// ---------------------------------------------------------------------------
__global__ __launch_bounds__(1024, 4) void k_conv1(
    const ushort* __restrict__ zt, const ushort* __restrict__ w1t,
    const float* __restrict__ b1, ushort* __restrict__ r1t)
{
    int b, h0; bhmap2r(b, h0);
    const int tid = threadIdx.x;
    const int wid = tid >> 6, lane = tid & 63, lq = lane & 15, quad = lane >> 4;
    const int row = wid >> 3;                    // output row within block
    const int pixbase = (wid & 1) * 64;
    const int ocbase = ((wid >> 1) & 3) * 32;
    const int rowoff = row * 16640;              // 130*128

    __shared__ __align__(16) ushort As[2 * 130 * 128];  // 66.6 KB halo x2 rows
    __shared__ __align__(16) ushort Bs[128 * 128];      // weights, 32 KB

    f32x4 acc[4][2];
#pragma unroll
    for (int i = 0; i < 4; i++)
#pragma unroll
        for (int j = 0; j < 2; j++)
#pragma unroll
            for (int r = 0; r < 4; r++) acc[i][j][r] = 0.f;

    const size_t zb = (size_t)b * HW * 128;
    for (int t9 = 0; t9 < 9; t9++) {
        const int dyi = t9 / 3, dx = t9 % 3;
        if (dx == 0) {                  // stage zt halo for BOTH rows, this dy
#pragma unroll
            for (int rr = 0; rr < 2; rr++) {
                int gy = h0 + rr + dyi - 1;
                for (int c = tid; c < 2080; c += 1024) {
                    int r = c >> 4, ch = c & 15, gx = r - 1;
                    uint4 v = {0, 0, 0, 0};
                    if ((unsigned)gy < 128u && (unsigned)gx < 128u)
                        v = *(const uint4*)(zt + zb + ((size_t)gy * 128 + gx) * 128 + ch * 8);
                    *(uint4*)&As[rr * 16640 + swz(r, ch)] = v;
                }
            }
        }
        // Bs: 2 async 16B/lane from pre-swizzled w1t (1024 thr cover 32 KB)
        {
            const ushort* wsrc = w1t + (size_t)t9 * 16384;
#pragma unroll
            for (int c = 0; c < 2; c++)
                gl2lds16(wsrc + c * 8192 + tid * 8, &Bs[c * 8192 + wid * 512]);
        }
        __syncthreads();
#pragma unroll
        for (int kk = 0; kk < 4; kk++) {
            int chunk = kk * 4 + quad;
            bf16x8 av[4], bv[2];
#pragma unroll
            for (int i = 0; i < 4; i++)
                av[i] = *(const bf16x8*)&As[rowoff + swz(pixbase + i * 16 + lq + dx, chunk)];
#pragma unroll
            for (int j = 0; j < 2; j++) bv[j] = *(const bf16x8*)&Bs[swz(ocbase + j * 16 + lq, chunk)];
#pragma unroll
            for (int i = 0; i < 4; i++)
#pragma unroll
                for (int j = 0; j < 2; j++)
                    acc[i][j] = __builtin_amdgcn_mfma_f32_16x16x32_bf16(av[i], bv[j], acc[i][j], 0, 0, 0);
        }
        __syncthreads();
    }

    size_t prow = ((size_t)b * HW + (h0 + row) * 128) * 128;
#pragma unroll
    for (int j = 0; j < 2; j++) {
        int oc = ocbase + j * 16 + lq;
        float bias = b1[oc];
#pragma unroll
        for (int i = 0; i < 4; i++)
#pragma unroll
            for (int r = 0; r < 4; r++) {
                int pix = pixbase + i * 16 + quad * 4 + r;
                r1t[prow + (size_t)pix * 128 + oc] = f2bf(fmaxf(acc[i][j][r] + bias, 0.f));
            }
    }
}

// ---------------------------------------------------------------------------
// k_conv2 v12: out = relu(x + (conv3x3(r1)+b2) * sigmoid(10*(clipU-0.5))).
// 1024 thr, 2 output rows per block (grid 256), mirror of conv1 v12:
// As weights 32 KB via gl2lds (2/thread); Bs[2][130][128] r1t halo per dy.
// Wave map: bit3=row, bit0=oc-half, bits1-2=pix-grp. M=oc, N=pix (NCHW
// fp32 stores coalesce). LDS 98.6 KB -> 1 block/CU.
// ---------------------------------------------------------------------------
__global__ __launch_bounds__(1024, 4) void k_conv2(
    const ushort* __restrict__ r1t, const ushort* __restrict__ w2t,
    const float* __restrict__ b2, const float* __restrict__ x,
    const float* __restrict__ U, float* __restrict__ out)
{
    int b, h0; bhmap2r(b, h0);
    const int tid = threadIdx.x;
    const int wid = tid >> 6, lane = tid & 63, lq = lane & 15, quad = lane >> 4;
    const int row = wid >> 3;
    const int mbase = (wid & 1) * 64;            // oc half
    const int nbase = ((wid >> 1) & 3) * 32;     // pix group
    const int rowoff = row * 16640;

    __shared__ __align__(16) ushort As[128 * 128];      // weights, 32 KB
    __shared__ __align__(16) ushort Bs[2 * 130 * 128];  // activ. halo, 66.6 KB

    f32x4 acc[4][2];
#pragma unroll
    for (int i = 0; i < 4; i++)
#pragma unroll
        for (int j = 0; j < 2; j++)
#pragma unroll
            for (int r = 0; r < 4; r++) acc[i][j][r] = 0.f;

    const size_t rb = (size_t)b * HW * 128;
    for (int t9 = 0; t9 < 9; t9++) {
        const int dyi = t9 / 3, dx = t9 % 3;
        if (dx == 0) {                  // stage r1t halo for BOTH rows, this dy
#pragma unroll
            for (int rr = 0; rr < 2; rr++) {
                int gy = h0 + rr + dyi - 1;
                for (int c = tid; c < 2080; c += 1024) {
                    int r = c >> 4, ch = c & 15, gx = r - 1;
                    uint4 v = {0, 0, 0, 0};
                    if ((unsigned)gy < 128u && (unsigned)gx < 128u)
                        v = *(const uint4*)(r1t + rb + ((size_t)gy * 128 + gx) * 128 + ch * 8);
                    *(uint4*)&Bs[rr * 16640 + swz(r, ch)] = v;
                }
            }
        }
        // As (weights): 2 async 16B/lane from pre-swizzled w2t
        {
            const ushort* wsrc = w2t + (size_t)t9 * 16384;
#pragma unroll
            for (int c = 0; c < 2; c++)
                gl2lds16(wsrc + c * 8192 + tid * 8, &As[c * 8192 + wid * 512]);
        }
        __syncthreads();
#pragma unroll
        for (int kk = 0; kk < 4; kk++) {
            int chunk = kk * 4 + quad;
            bf16x8 av[4], bv[2];
#pragma unroll
            for (int i = 0; i < 4; i++) av[i] = *(const bf16x8*)&As[swz(mbase + i * 16 + lq, chunk)];
#pragma unroll
            for (int j = 0; j < 2; j++)
                bv[j] = *(const bf16x8*)&Bs[rowoff + swz(nbase + j * 16 + lq + dx, chunk)];
#pragma unroll
            for (int i = 0; i < 4; i++)
#pragma unroll
                for (int j = 0; j < 2; j++)
                    acc[i][j] = __builtin_amdgcn_mfma_f32_16x16x32_bf16(av[i], bv[j], acc[i][j], 0, 0, 0);
        }
        __syncthreads();
    }

    const int h = h0 + row;
#pragma unroll
    for (int j = 0; j < 2; j++) {
        int pix = nbase + j * 16 + lq;
        float u = U[(size_t)b * HW + h * 128 + pix];
        u = fminf(fmaxf(u, 0.f), 1.f);
        float g = 1.f / (1.f + __expf(-10.f * (u - 0.5f)));
#pragma unroll
        for (int i = 0; i < 4; i++) {
            f32x4 b4 = *(const f32x4*)&b2[mbase + i * 16 + quad * 4];
#pragma unroll
            for (int r = 0; r < 4; r++) {
                int oc = mbase + i * 16 + quad * 4 + r;
                size_t idx = ((size_t)(b * 128 + oc)) * HW + h * 128 + pix;
                float v = acc[i][j][r] + b4[r];
                out[idx] = fmaxf(x[idx] + v * g, 0.f);
            }
        }
    }
}

// ---------------------------------------------------------------------------
extern "C" void kernel_launch(void* const* d_in, const int* in_sizes, int n_in,
                              void* d_out, int out_size, void* d_ws, size_t ws_size,
                              hipStream_t stream)
{
    const float* x     = (const float*)d_in[0];
    const float* U     = (const float*)d_in[1];
    const float* w_om  = (const float*)d_in[2];
    const float* b_om  = (const float*)d_in[3];
    const float* w_dcn = (const float*)d_in[4];
    const float* b_dcn = (const float*)d_in[5];
    const float* w1    = (const float*)d_in[6];
    const float* b1    = (const float*)d_in[7];
    const float* w2    = (const float*)d_in[8];
    const float* b2    = (const float*)d_in[9];
    float* out = (float*)d_out;

    char* p = (char*)d_ws;
    ushort* xt   = (ushort*)p; p += (size_t)4 * HW * 128 * 2;   // 16.78 MB
    ushort* zt   = (ushort*)p; p += (size_t)4 * HW * 128 * 2;
    ushort* r1t  = (ushort*)p; p += (size_t)4 * HW * 128 * 2;
    float*  omt  = (float*)p;  p += (size_t)4 * HW * 32 * 4;    // 8.39 MB
    ushort* wdt  = (ushort*)p; p += 147456 * 2;
    ushort* w1t  = (ushort*)p; p += 147456 * 2;
    ushort* w2t  = (ushort*)p; p += 147456 * 2;
    ushort* womt = (ushort*)p; p += 36864 * 2;
    float*  womu = (float*)p;  p += 288 * 4;

    prep_w<<<576, 256, 0, stream>>>(w_dcn, w1, w2, w_om, wdt, w1t, w2t, womt, womu);
    prep_xt<<<dim3(128, 4), 256, 0, stream>>>(x, xt);
    k_om<<<dim3(128, 4), 512, 0, stream>>>(xt, U, womt, womu, b_om, omt);
    k_dcn<<<dim3(128, 4), 512, 0, stream>>>(xt, omt, wdt, b_dcn, zt);
    k_conv1<<<dim3(64, 4), 1024, 0, stream>>>(zt, w1t, b1, r1t);
    k_conv2<<<dim3(64, 4), 1024, 0, stream>>>(r1t, w2t, b2, x, U, out);
}